// Round 7
// baseline (2937.002 us; speedup 1.0000x reference)
//
#include <hip/hip_runtime.h>
#include <math.h>

#define N_NODES 60000
#define N_EDGES 360000
#define N_GRAPH 64
#define HID 512
#define NCLS 1000
#define BN_EPS 1e-5f
#define NS ((size_t)N_NODES * HID)
#define NB 235  // (N_NODES + 255) / 256

typedef __bf16 bf16x8 __attribute__((ext_vector_type(8)));
typedef float f32x4 __attribute__((ext_vector_type(4)));

static __device__ __forceinline__ unsigned short f2bf(float f) {
  unsigned u = __float_as_uint(f);
  unsigned r = (u + 0x7fffu + ((u >> 16) & 1u)) >> 16;  // RNE
  return (unsigned short)r;
}
static __device__ __forceinline__ float bfLo(unsigned u) { return __uint_as_float(u << 16); }
static __device__ __forceinline__ float bfHi(unsigned u) { return __uint_as_float(u & 0xffff0000u); }
static __device__ __forceinline__ unsigned packbf(float a, float b) {
  return (unsigned)f2bf(a) | ((unsigned)f2bf(b) << 16);
}

__global__ void write_sentinel(float* out, float v) { out[0] = v; }

// ---------------------------------------------------------------------------
// Weight fp32 -> bf16 transpose: Wt[n][k] = bf16(W[k][n]).  32x32 tiles.
// ---------------------------------------------------------------------------
__global__ __launch_bounds__(256) void wtrans(const float* __restrict__ W,
                                              unsigned short* __restrict__ Wt,
                                              int K, int N) {
  __shared__ float sh[32][33];
  int kt = blockIdx.x * 32, nt = blockIdx.y * 32;
  int tx = threadIdx.x & 31, ty = threadIdx.x >> 5;  // ty 0..7
#pragma unroll
  for (int i = 0; i < 4; ++i)
    sh[ty + i * 8][tx] = W[(size_t)(kt + ty + i * 8) * N + nt + tx];
  __syncthreads();
#pragma unroll
  for (int i = 0; i < 4; ++i)
    Wt[(size_t)(nt + ty + i * 8) * K + kt + tx] = f2bf(sh[tx][ty + i * 8]);
}

// ---------------------------------------------------------------------------
// Degree / CSR build
// ---------------------------------------------------------------------------
__global__ __launch_bounds__(256) void count_deg(const int* __restrict__ dst,
                                                 int* __restrict__ deg, int E) {
  int e = blockIdx.x * 256 + threadIdx.x;
  if (e < E) atomicAdd(&deg[dst[e]], 1);
}

__global__ __launch_bounds__(256) void make_invdeg(const int* __restrict__ deg,
                                                   float* __restrict__ inv, int n) {
  int i = blockIdx.x * 256 + threadIdx.x;
  if (i < n) inv[i] = 1.0f / fmaxf((float)deg[i], 1.0f);
}

// ---- parallel 3-phase exclusive scan of deg -> rowptr -----------------------
__global__ __launch_bounds__(256) void scan_part(const int* __restrict__ deg,
                                                 int* __restrict__ bsum, int n) {
  __shared__ int sh[256];
  int i = blockIdx.x * 256 + threadIdx.x;
  sh[threadIdx.x] = (i < n) ? deg[i] : 0;
  __syncthreads();
  for (int off = 128; off; off >>= 1) {
    if (threadIdx.x < off) sh[threadIdx.x] += sh[threadIdx.x + off];
    __syncthreads();
  }
  if (threadIdx.x == 0) bsum[blockIdx.x] = sh[0];
}

__global__ __launch_bounds__(256) void scan_bsums(int* __restrict__ bsum, int nb) {
  __shared__ int sh[256];
  int t = threadIdx.x;
  int v = (t < nb) ? bsum[t] : 0;
  sh[t] = v;
  __syncthreads();
  for (int off = 1; off < 256; off <<= 1) {
    int u = (t >= off) ? sh[t - off] : 0;
    __syncthreads();
    sh[t] += u;
    __syncthreads();
  }
  if (t < nb) bsum[t] = sh[t] - v;  // exclusive
}

__global__ __launch_bounds__(256) void scan_final(const int* __restrict__ deg,
                                                  const int* __restrict__ bsum,
                                                  int* __restrict__ rowptr, int n) {
  __shared__ int sh[256];
  int t = threadIdx.x;
  int i = blockIdx.x * 256 + t;
  int v = (i < n) ? deg[i] : 0;
  sh[t] = v;
  __syncthreads();
  for (int off = 1; off < 256; off <<= 1) {
    int u = (t >= off) ? sh[t - off] : 0;
    __syncthreads();
    sh[t] += u;
    __syncthreads();
  }
  if (i < n) rowptr[i + 1] = bsum[blockIdx.x] + sh[t];
  if (i == 0) rowptr[0] = 0;
}

__global__ __launch_bounds__(256) void fill_csr(const int* __restrict__ src,
                                                const int* __restrict__ dst,
                                                const int* __restrict__ rowptr,
                                                int* __restrict__ fillc,
                                                int* __restrict__ esrc, int E) {
  int e = blockIdx.x * 256 + threadIdx.x;
  if (e < E) {
    int d = dst[e];
    int pos = rowptr[d] + atomicAdd(&fillc[d], 1);
    esrc[pos] = src[e];
  }
}

// LDS-histogram batch count (batch sorted -> heavy same-address contention if
// done with global atomics; per-block LDS bins then <=64 global atomics/block)
__global__ __launch_bounds__(256) void bcount(const int* __restrict__ batch,
                                              float* __restrict__ bcnt, int n) {
  __shared__ int h[N_GRAPH];
  if (threadIdx.x < N_GRAPH) h[threadIdx.x] = 0;
  __syncthreads();
  int i = blockIdx.x * 256 + threadIdx.x;
  if (i < n) atomicAdd(&h[batch[i]], 1);
  __syncthreads();
  if (threadIdx.x < N_GRAPH && h[threadIdx.x])
    atomicAdd(&bcnt[threadIdx.x], (float)h[threadIdx.x]);
}

// ---------------------------------------------------------------------------
// MFMA GEMM v3 — LDS-free, barrier-free k-loop:
//   out[M x 512](bf16) = X[M x K] @ W[K x 512] (+ bias), Wt = W^T bf16 [512][ldw]
// 512 threads = 8 waves; wave wv covers cols [wv*64, wv*64+64). BM=64, BK=32.
// Both A and B MFMA fragments are 16B contiguous runs of row-major X / Wt ->
// loaded directly from global (L1/L2-served; A rows shared by all 8 waves).
// In-place safety: single __syncthreads() between k-loop and epilogue. Each
// wave's A-loads are consumed by its MFMAs before it reaches the barrier, so
// after the barrier no wave can still read rows this block is about to store.
// ---------------------------------------------------------------------------
__global__ __launch_bounds__(512) void gemm_mfma(
    const void* __restrict__ Xv, int ldx, int K, int xBf16,
    const unsigned short* __restrict__ Wt, int ldw,
    const float* __restrict__ bias,
    unsigned short* __restrict__ outB, int M) {
  const int tid = threadIdx.x;
  const int bm = blockIdx.x * 64;
  const int wv = tid >> 6, lane = tid & 63;
  const int lm = lane & 15, quad = lane >> 4, lk = quad * 8;
  const int cb = wv * 64;

  f32x4 zero;
  zero[0] = 0.f; zero[1] = 0.f; zero[2] = 0.f; zero[3] = 0.f;
  f32x4 acc[4][4];
#pragma unroll
  for (int i = 0; i < 4; ++i)
#pragma unroll
    for (int j = 0; j < 4; ++j) acc[i][j] = zero;

  bool arow_ok[4];
#pragma unroll
  for (int i = 0; i < 4; ++i) arow_ok[i] = (bm + i * 16 + lm) < M;

  for (int kt = 0; kt < K; kt += 32) {
    bf16x8 af[4], bfr[4];
    if (xBf16) {
      const unsigned short* Xb = (const unsigned short*)Xv;
#pragma unroll
      for (int i = 0; i < 4; ++i) {
        af[i] = (bf16x8)0;
        if (arow_ok[i])
          af[i] = *(const bf16x8*)(Xb + (size_t)(bm + i * 16 + lm) * ldx + kt + lk);
      }
    } else {
      const float* Xf = (const float*)Xv;
#pragma unroll
      for (int i = 0; i < 4; ++i) {
        af[i] = (bf16x8)0;
        if (arow_ok[i]) {
          const float* xp = Xf + (size_t)(bm + i * 16 + lm) * ldx + kt + lk;
          float4 f0 = *(const float4*)xp;
          float4 f1 = *(const float4*)(xp + 4);
          uint4 u;
          u.x = packbf(f0.x, f0.y); u.y = packbf(f0.z, f0.w);
          u.z = packbf(f1.x, f1.y); u.w = packbf(f1.z, f1.w);
          af[i] = *(const bf16x8*)&u;
        }
      }
    }
#pragma unroll
    for (int j = 0; j < 4; ++j)
      bfr[j] = *(const bf16x8*)(Wt + (size_t)(cb + j * 16 + lm) * ldw + kt + lk);
#pragma unroll
    for (int i = 0; i < 4; ++i)
#pragma unroll
      for (int j = 0; j < 4; ++j)
        acc[i][j] = __builtin_amdgcn_mfma_f32_16x16x32_bf16(af[i], bfr[j], acc[i][j], 0, 0, 0);
  }

  __syncthreads();  // all waves finished reading X rows of this strip

  const int qr = quad * 4;
#pragma unroll
  for (int j = 0; j < 4; ++j) {
    int col = cb + j * 16 + lm;
    float bvv = bias ? bias[col] : 0.f;
#pragma unroll
    for (int i = 0; i < 4; ++i) {
      int rbase = bm + i * 16 + qr;
#pragma unroll
      for (int r = 0; r < 4; ++r) {
        int row = rbase + r;
        if (row < M) outB[(size_t)row * 512 + col] = f2bf(acc[i][j][r] + bvv);
      }
    }
  }
}

// ---------------------------------------------------------------------------
// Fused aggregation + L2 row-norm (one wave per dst node, CSR gather):
//   row = Ya[d] + invdeg[d] * sum_{e in CSR[d]} Yb[esrc[e]];  Ya[d] = row/||row||
// ---------------------------------------------------------------------------
__global__ __launch_bounds__(256) void aggr_norm(
    unsigned short* __restrict__ Ya, const unsigned short* __restrict__ Yb,
    const int* __restrict__ rowptr, const int* __restrict__ esrc,
    const float* __restrict__ invdeg, int M) {
  int d = blockIdx.x * 4 + (threadIdx.x >> 6);
  int lane = threadIdx.x & 63;
  if (d >= M) return;
  float acc[8] = {0.f, 0.f, 0.f, 0.f, 0.f, 0.f, 0.f, 0.f};
  int beg = rowptr[d], end = rowptr[d + 1];
  for (int e = beg; e < end; ++e) {
    int s = esrc[e];
    uint4 u = *(const uint4*)(Yb + (size_t)s * 512 + lane * 8);
    acc[0] += bfLo(u.x); acc[1] += bfHi(u.x);
    acc[2] += bfLo(u.y); acc[3] += bfHi(u.y);
    acc[4] += bfLo(u.z); acc[5] += bfHi(u.z);
    acc[6] += bfLo(u.w); acc[7] += bfHi(u.w);
  }
  float iv = invdeg[d];
  uint4 a = *(const uint4*)(Ya + (size_t)d * 512 + lane * 8);
  float r0 = bfLo(a.x) + iv * acc[0], r1 = bfHi(a.x) + iv * acc[1];
  float r2 = bfLo(a.y) + iv * acc[2], r3 = bfHi(a.y) + iv * acc[3];
  float r4 = bfLo(a.z) + iv * acc[4], r5 = bfHi(a.z) + iv * acc[5];
  float r6 = bfLo(a.w) + iv * acc[6], r7 = bfHi(a.w) + iv * acc[7];
  float ss = r0 * r0 + r1 * r1 + r2 * r2 + r3 * r3
           + r4 * r4 + r5 * r5 + r6 * r6 + r7 * r7;
#pragma unroll
  for (int o = 32; o; o >>= 1) ss += __shfl_xor(ss, o, 64);
  float inv = 1.0f / fmaxf(sqrtf(ss), 1e-12f);
  uint4 o4;
  o4.x = packbf(r0 * inv, r1 * inv);
  o4.y = packbf(r2 * inv, r3 * inv);
  o4.z = packbf(r4 * inv, r5 * inv);
  o4.w = packbf(r6 * inv, r7 * inv);
  *(uint4*)(Ya + (size_t)d * 512 + lane * 8) = o4;
}

// ---------------------------------------------------------------------------
// BN stats over bf16: sums[0..511]=sum, sums[512..1023]=sumsq
// ---------------------------------------------------------------------------
__global__ __launch_bounds__(256) void bn_stats(const unsigned short* __restrict__ T,
                                                int M, float* __restrict__ sums) {
  const int t = threadIdx.x;
  int r0 = blockIdx.x * 128;
  int rend = min(r0 + 128, M);
  float s0 = 0.f, q0 = 0.f, s1 = 0.f, q1 = 0.f;
  for (int r = r0; r < rend; ++r) {
    float a = __uint_as_float((unsigned)T[(size_t)r * 512 + t] << 16);
    float b = __uint_as_float((unsigned)T[(size_t)r * 512 + t + 256] << 16);
    s0 += a; q0 += a * a; s1 += b; q1 += b * b;
  }
  atomicAdd(&sums[t], s0);
  atomicAdd(&sums[t + 256], s1);
  atomicAdd(&sums[512 + t], q0);
  atomicAdd(&sums[512 + t + 256], q1);
}

// BN apply + ReLU (+ optional residual); bf16 in/out, 2 cols per thread.
__global__ __launch_bounds__(256) void bn_apply(const unsigned short* __restrict__ U,
                                                unsigned short* __restrict__ H,
                                                const float* __restrict__ sums,
                                                const float* __restrict__ g,
                                                const float* __restrict__ be,
                                                int M, int residual) {
  size_t i2 = (size_t)blockIdx.x * 256 + threadIdx.x;
  if (i2 >= NS / 2) return;
  int c = ((int)(i2 & 255)) * 2;
  float invM = 1.0f / (float)M;
  float m0 = sums[c] * invM, m1 = sums[c + 1] * invM;
  float v0 = sums[512 + c] * invM - m0 * m0;
  float v1 = sums[512 + c + 1] * invM - m1 * m1;
  float k0 = rsqrtf(v0 + BN_EPS) * g[c], k1 = rsqrtf(v1 + BN_EPS) * g[c + 1];
  unsigned u = ((const unsigned*)U)[i2];
  float x0 = fmaxf((bfLo(u) - m0) * k0 + be[c], 0.f);
  float x1 = fmaxf((bfHi(u) - m1) * k1 + be[c + 1], 0.f);
  if (residual) {
    unsigned hv = ((const unsigned*)H)[i2];
    x0 += bfLo(hv);
    x1 += bfHi(hv);
  }
  ((unsigned*)H)[i2] = packbf(x0, x1);
}

// ---------------------------------------------------------------------------
// Attention pool, sorted-batch segmented version. Watt read per-lane from
// global (was LDS with 16-way bank conflicts).
// ---------------------------------------------------------------------------
__global__ __launch_bounds__(256) void att_pool2(const unsigned short* __restrict__ H,
                                                 const int* __restrict__ batch,
                                                 const float* __restrict__ Watt,
                                                 float* __restrict__ hg, int M) {
  __shared__ float fsh[256];
  __shared__ int bsh[256];
  const int tid = threadIdx.x;
  const int base = blockIdx.x * 256;
  bsh[tid] = (base + tid < M) ? batch[base + tid] : -1;
  const int wv = tid >> 6, lane = tid & 63;
  float4 wa0 = *(const float4*)(Watt + lane * 8);
  float4 wa1 = *(const float4*)(Watt + lane * 8 + 4);
  __syncthreads();
  for (int i = wv; i < 256; i += 4) {
    int node = base + i;
    float dot = 0.f;
    if (node < M) {
      uint4 u = *(const uint4*)(H + (size_t)node * 512 + lane * 8);
      dot = bfLo(u.x) * wa0.x + bfHi(u.x) * wa0.y
          + bfLo(u.y) * wa0.z + bfHi(u.y) * wa0.w
          + bfLo(u.z) * wa1.x + bfHi(u.z) * wa1.y
          + bfLo(u.w) * wa1.z + bfHi(u.w) * wa1.w;
    }
#pragma unroll
    for (int o = 32; o; o >>= 1) dot += __shfl_xor(dot, o, 64);
    if (lane == 0) fsh[i] = 0.5f * (1.0f + 1.0f / (1.0f + expf(-dot)));
  }
  __syncthreads();
  float a0 = 0.f, a1 = 0.f;
  int cur = bsh[0];
  for (int i = 0; i < 256; ++i) {
    int node = base + i;
    if (node >= M) break;
    int b = bsh[i];
    if (b != cur) {
      atomicAdd(&hg[(size_t)cur * 512 + tid * 2], a0);
      atomicAdd(&hg[(size_t)cur * 512 + tid * 2 + 1], a1);
      a0 = a1 = 0.f;
      cur = b;
    }
    unsigned u = *(const unsigned*)(H + (size_t)node * 512 + tid * 2);
    float f = fsh[i];
    a0 += bfLo(u) * f;
    a1 += bfHi(u) * f;
  }
  if (cur >= 0) {
    atomicAdd(&hg[(size_t)cur * 512 + tid * 2], a0);
    atomicAdd(&hg[(size_t)cur * 512 + tid * 2 + 1], a1);
  }
}

// ---------------------------------------------------------------------------
// Readout: out[g, n] = (hg[g]/bcnt[g]) . Wread[:, n]
// ---------------------------------------------------------------------------
__global__ __launch_bounds__(256) void readout(const float* __restrict__ hg,
                                               const float* __restrict__ bcnt,
                                               const float* __restrict__ Wr,
                                               float* __restrict__ out) {
  __shared__ float sh[HID];
  int g = blockIdx.x;
  int n = blockIdx.y * 256 + threadIdx.x;
  float inv = 1.0f / fmaxf(bcnt[g], 1.0f);
  for (int k = threadIdx.x; k < HID; k += 256) sh[k] = hg[(size_t)g * HID + k] * inv;
  __syncthreads();
  if (n < NCLS) {
    float acc = 0.f;
    for (int k = 0; k < HID; ++k) acc += sh[k] * Wr[(size_t)k * NCLS + n];
    out[(size_t)g * NCLS + n] = acc;
  }
}

// ---------------------------------------------------------------------------
extern "C" void kernel_launch(void* const* d_in, const int* in_sizes, int n_in,
                              void* d_out, int out_size, void* d_ws, size_t ws_size,
                              hipStream_t stream) {
  const float* x       = (const float*)d_in[0];
  const int*   ei      = (const int*)d_in[1];
  const int*   batch   = (const int*)d_in[2];
  const float* W_embed = (const float*)d_in[3];
  const float* W1      = (const float*)d_in[4];
  const float* b1      = (const float*)d_in[5];
  const float* g1      = (const float*)d_in[6];
  const float* be1     = (const float*)d_in[7];
  const float* W2      = (const float*)d_in[8];
  const float* b2      = (const float*)d_in[9];
  const float* g2      = (const float*)d_in[10];
  const float* be2     = (const float*)d_in[11];
  const float* Watt    = (const float*)d_in[12];
  const float* Wread   = (const float*)d_in[13];
  float* out = (float*)d_out;

  const int* srcIdx = ei;
  const int* dstIdx = ei + N_EDGES;

  char* p = (char*)d_ws;
  unsigned short* B0 = (unsigned short*)p; p += NS * 2;   // h (residual)
  unsigned short* B1 = (unsigned short*)p; p += NS * 2;   // Ya / T
  unsigned short* B2 = (unsigned short*)p; p += NS * 2;   // Yb
  unsigned short* WtE = (unsigned short*)p; p += (size_t)512 * 256 * 2;
  unsigned short* Wt1 = (unsigned short*)p; p += (size_t)3 * 512 * 1024 * 2;
  unsigned short* Wt2 = (unsigned short*)p; p += (size_t)3 * 512 * 1024 * 2;
  float* hg     = (float*)p; p += (size_t)N_GRAPH * HID * 4;
  float* sums   = (float*)p; p += 1024 * 4;
  float* invdeg = (float*)p; p += (size_t)N_NODES * 4;
  float* bcnt   = (float*)p; p += 256;
  int* deg      = (int*)p;   p += (size_t)N_NODES * 4;
  int* fillc    = (int*)p;   p += (size_t)N_NODES * 4;
  int* esrc     = (int*)p;   p += (size_t)N_EDGES * 4;
  int* rowptr   = (int*)p;   p += (size_t)(N_NODES + 1) * 4;
  int* bsum     = (int*)p;   p += (size_t)NB * 4;
  size_t need = (size_t)(p - (char*)d_ws);
  if (ws_size < need) {  // diagnostic sentinel
    write_sentinel<<<1, 1, 0, stream>>>(out, (float)need);
    return;
  }

  // ---- weight prep (fp32 -> bf16, transposed [N][K])
  wtrans<<<dim3(8, 16), 256, 0, stream>>>(W_embed, WtE, 256, 512);
  for (int l = 0; l < 3; ++l) {
    wtrans<<<dim3(32, 16), 256, 0, stream>>>(W1 + (size_t)l * 1024 * 512,
                                             Wt1 + (size_t)l * 512 * 1024, 1024, 512);
    wtrans<<<dim3(32, 16), 256, 0, stream>>>(W2 + (size_t)l * 1024 * 512,
                                             Wt2 + (size_t)l * 512 * 1024, 1024, 512);
  }

  // ---- CSR build (parallel scan)
  hipMemsetAsync(deg, 0, N_NODES * sizeof(int), stream);
  hipMemsetAsync(fillc, 0, N_NODES * sizeof(int), stream);
  count_deg<<<(N_EDGES + 255) / 256, 256, 0, stream>>>(dstIdx, deg, N_EDGES);
  make_invdeg<<<(N_NODES + 255) / 256, 256, 0, stream>>>(deg, invdeg, N_NODES);
  scan_part<<<NB, 256, 0, stream>>>(deg, bsum, N_NODES);
  scan_bsums<<<1, 256, 0, stream>>>(bsum, NB);
  scan_final<<<NB, 256, 0, stream>>>(deg, bsum, rowptr, N_NODES);
  fill_csr<<<(N_EDGES + 255) / 256, 256, 0, stream>>>(srcIdx, dstIdx, rowptr, fillc,
                                                      esrc, N_EDGES);

  const int mgrid = (N_NODES + 63) / 64;   // 938, 1-D row strips (in-place safety)
  const int ngrid = (N_NODES + 3) / 4;
  const int egrid = (int)((NS / 2 + 255) / 256);

  // h = x @ W_embed
  gemm_mfma<<<mgrid, 512, 0, stream>>>(x, 256, 256, 0, WtE, 256, nullptr, B0, N_NODES);

  for (int l = 0; l < 3; ++l) {
    const unsigned short* Wt1l = Wt1 + (size_t)l * 512 * 1024;
    const unsigned short* Wt2l = Wt2 + (size_t)l * 512 * 1024;
    // ---- SAGE 1
    gemm_mfma<<<mgrid, 512, 0, stream>>>(B0, 512, 512, 1, Wt1l + 512, 1024,
                                         nullptr, B2, N_NODES);        // Yb = h@Wb1
    gemm_mfma<<<mgrid, 512, 0, stream>>>(B0, 512, 512, 1, Wt1l, 1024,
                                         b1 + l * 512, B1, N_NODES);   // Ya = h@Wa1+b
    aggr_norm<<<ngrid, 256, 0, stream>>>(B1, B2, rowptr, esrc, invdeg, N_NODES);
    hipMemsetAsync(sums, 0, 1024 * sizeof(float), stream);
    bn_stats<<<(N_NODES + 127) / 128, 256, 0, stream>>>(B1, N_NODES, sums);
    bn_apply<<<egrid, 256, 0, stream>>>(B1, B1, sums, g1 + l * 512,
                                        be1 + l * 512, N_NODES, 0);
    // ---- SAGE 2 + residual
    gemm_mfma<<<mgrid, 512, 0, stream>>>(B1, 512, 512, 1, Wt2l + 512, 1024,
                                         nullptr, B2, N_NODES);        // Yb
    gemm_mfma<<<mgrid, 512, 0, stream>>>(B1, 512, 512, 1, Wt2l, 1024,
                                         b2 + l * 512, B1, N_NODES);   // in-place, safe
    aggr_norm<<<ngrid, 256, 0, stream>>>(B1, B2, rowptr, esrc, invdeg, N_NODES);
    hipMemsetAsync(sums, 0, 1024 * sizeof(float), stream);
    bn_stats<<<(N_NODES + 127) / 128, 256, 0, stream>>>(B1, N_NODES, sums);
    bn_apply<<<egrid, 256, 0, stream>>>(B1, B0, sums, g2 + l * 512,
                                        be2 + l * 512, N_NODES, 1);
  }

  // ---- pooling + readout
  hipMemsetAsync(hg, 0, (size_t)N_GRAPH * HID * sizeof(float), stream);
  hipMemsetAsync(bcnt, 0, N_GRAPH * sizeof(float), stream);
  bcount<<<NB, 256, 0, stream>>>(batch, bcnt, N_NODES);
  att_pool2<<<NB, 256, 0, stream>>>(B0, batch, Watt, hg, N_NODES);
  readout<<<dim3(N_GRAPH, 4), 256, 0, stream>>>(hg, bcnt, Wread, out);
}

// Round 9
// 2318.315 us; speedup vs baseline: 1.2669x; 1.2669x over previous
//
#include <hip/hip_runtime.h>
#include <math.h>

#define N_NODES 60000
#define N_EDGES 360000
#define N_GRAPH 64
#define HID 512
#define NCLS 1000
#define BN_EPS 1e-5f
#define NS ((size_t)N_NODES * HID)
#define NB 235  // (N_NODES + 255) / 256

typedef __bf16 bf16x8 __attribute__((ext_vector_type(8)));
typedef float f32x4 __attribute__((ext_vector_type(4)));

static __device__ __forceinline__ unsigned short f2bf(float f) {
  unsigned u = __float_as_uint(f);
  unsigned r = (u + 0x7fffu + ((u >> 16) & 1u)) >> 16;  // RNE
  return (unsigned short)r;
}
static __device__ __forceinline__ float bfLo(unsigned u) { return __uint_as_float(u << 16); }
static __device__ __forceinline__ float bfHi(unsigned u) { return __uint_as_float(u & 0xffff0000u); }
static __device__ __forceinline__ unsigned packbf(float a, float b) {
  return (unsigned)f2bf(a) | ((unsigned)f2bf(b) << 16);
}

__global__ void write_sentinel(float* out, float v) { out[0] = v; }

// ---------------------------------------------------------------------------
// Weight fp32 -> bf16 transpose: Wt[n][k] = bf16(W[k][n]).  32x32 tiles.
// ---------------------------------------------------------------------------
__global__ __launch_bounds__(256) void wtrans(const float* __restrict__ W,
                                              unsigned short* __restrict__ Wt,
                                              int K, int N) {
  __shared__ float sh[32][33];
  int kt = blockIdx.x * 32, nt = blockIdx.y * 32;
  int tx = threadIdx.x & 31, ty = threadIdx.x >> 5;  // ty 0..7
#pragma unroll
  for (int i = 0; i < 4; ++i)
    sh[ty + i * 8][tx] = W[(size_t)(kt + ty + i * 8) * N + nt + tx];
  __syncthreads();
#pragma unroll
  for (int i = 0; i < 4; ++i)
    Wt[(size_t)(nt + ty + i * 8) * K + kt + tx] = f2bf(sh[tx][ty + i * 8]);
}

// ---------------------------------------------------------------------------
// Degree / CSR build
// ---------------------------------------------------------------------------
__global__ __launch_bounds__(256) void count_deg(const int* __restrict__ dst,
                                                 int* __restrict__ deg, int E) {
  int e = blockIdx.x * 256 + threadIdx.x;
  if (e < E) atomicAdd(&deg[dst[e]], 1);
}

__global__ __launch_bounds__(256) void make_invdeg(const int* __restrict__ deg,
                                                   float* __restrict__ inv, int n) {
  int i = blockIdx.x * 256 + threadIdx.x;
  if (i < n) inv[i] = 1.0f / fmaxf((float)deg[i], 1.0f);
}

// ---- parallel 3-phase exclusive scan of deg -> rowptr -----------------------
__global__ __launch_bounds__(256) void scan_part(const int* __restrict__ deg,
                                                 int* __restrict__ bsum, int n) {
  __shared__ int sh[256];
  int i = blockIdx.x * 256 + threadIdx.x;
  sh[threadIdx.x] = (i < n) ? deg[i] : 0;
  __syncthreads();
  for (int off = 128; off; off >>= 1) {
    if (threadIdx.x < off) sh[threadIdx.x] += sh[threadIdx.x + off];
    __syncthreads();
  }
  if (threadIdx.x == 0) bsum[blockIdx.x] = sh[0];
}

__global__ __launch_bounds__(256) void scan_bsums(int* __restrict__ bsum, int nb) {
  __shared__ int sh[256];
  int t = threadIdx.x;
  int v = (t < nb) ? bsum[t] : 0;
  sh[t] = v;
  __syncthreads();
  for (int off = 1; off < 256; off <<= 1) {
    int u = (t >= off) ? sh[t - off] : 0;
    __syncthreads();
    sh[t] += u;
    __syncthreads();
  }
  if (t < nb) bsum[t] = sh[t] - v;  // exclusive
}

__global__ __launch_bounds__(256) void scan_final(const int* __restrict__ deg,
                                                  const int* __restrict__ bsum,
                                                  int* __restrict__ rowptr, int n) {
  __shared__ int sh[256];
  int t = threadIdx.x;
  int i = blockIdx.x * 256 + t;
  int v = (i < n) ? deg[i] : 0;
  sh[t] = v;
  __syncthreads();
  for (int off = 1; off < 256; off <<= 1) {
    int u = (t >= off) ? sh[t - off] : 0;
    __syncthreads();
    sh[t] += u;
    __syncthreads();
  }
  if (i < n) rowptr[i + 1] = bsum[blockIdx.x] + sh[t];
  if (i == 0) rowptr[0] = 0;
}

__global__ __launch_bounds__(256) void fill_csr(const int* __restrict__ src,
                                                const int* __restrict__ dst,
                                                const int* __restrict__ rowptr,
                                                int* __restrict__ fillc,
                                                int* __restrict__ esrc, int E) {
  int e = blockIdx.x * 256 + threadIdx.x;
  if (e < E) {
    int d = dst[e];
    int pos = rowptr[d] + atomicAdd(&fillc[d], 1);
    esrc[pos] = src[e];
  }
}

// LDS-histogram batch count (sorted batch -> same-address contention fix)
__global__ __launch_bounds__(256) void bcount(const int* __restrict__ batch,
                                              float* __restrict__ bcnt, int n) {
  __shared__ int h[N_GRAPH];
  if (threadIdx.x < N_GRAPH) h[threadIdx.x] = 0;
  __syncthreads();
  int i = blockIdx.x * 256 + threadIdx.x;
  if (i < n) atomicAdd(&h[batch[i]], 1);
  __syncthreads();
  if (threadIdx.x < N_GRAPH && h[threadIdx.x])
    atomicAdd(&bcnt[threadIdx.x], (float)h[threadIdx.x]);
}

// ---------------------------------------------------------------------------
// Tiled MFMA GEMM (m93 structure): out[M x 512](bf16) = X[M x K] @ W (+ bias)
// Wt = W^T bf16 [512][ldw].  128x128 tile, BK=32, 256 thr = 4 waves (2x2 of
// 64x64).  Coalesced 16B staging loads -> padded LDS (stride 40 halfs: only
// free 2-way bank conflicts) -> b128 fragment reads -> 16 MFMAs/wave/ktile.
// NOT in-place safe (grid.y = 4).
// ---------------------------------------------------------------------------
__global__ __launch_bounds__(256) void gemm_tiled(
    const void* __restrict__ Xv, int ldx, int K, int xBf16,
    const unsigned short* __restrict__ Wt, int ldw,
    const float* __restrict__ bias,
    unsigned short* __restrict__ outB, int M) {
  __shared__ __align__(16) unsigned short As[128][40];
  __shared__ __align__(16) unsigned short Bs[128][40];
  const int tid = threadIdx.x;
  const int bm = blockIdx.x * 128;
  const int bn = blockIdx.y * 128;
  const int wv = tid >> 6, lane = tid & 63;
  const int wm = (wv >> 1) * 64, wn = (wv & 1) * 64;
  const int lm = lane & 15, quad = lane >> 4, lk = quad * 8;
  const int srow = tid >> 2, sseg = (tid & 3) * 8;

  f32x4 zero;
  zero[0] = 0.f; zero[1] = 0.f; zero[2] = 0.f; zero[3] = 0.f;
  f32x4 acc[4][4];
#pragma unroll
  for (int i = 0; i < 4; ++i)
#pragma unroll
    for (int j = 0; j < 4; ++j) acc[i][j] = zero;

  const int r0 = bm + srow, r1 = bm + 64 + srow;
  for (int kt = 0; kt < K; kt += 32) {
    uint4 a0 = make_uint4(0, 0, 0, 0), a1 = make_uint4(0, 0, 0, 0);
    if (xBf16) {
      const unsigned short* Xb = (const unsigned short*)Xv;
      if (r0 < M) a0 = *(const uint4*)(Xb + (size_t)r0 * ldx + kt + sseg);
      if (r1 < M) a1 = *(const uint4*)(Xb + (size_t)r1 * ldx + kt + sseg);
    } else {
      const float* Xf = (const float*)Xv;
      if (r0 < M) {
        const float* xp = Xf + (size_t)r0 * ldx + kt + sseg;
        float4 f0 = *(const float4*)xp, f1 = *(const float4*)(xp + 4);
        a0.x = packbf(f0.x, f0.y); a0.y = packbf(f0.z, f0.w);
        a0.z = packbf(f1.x, f1.y); a0.w = packbf(f1.z, f1.w);
      }
      if (r1 < M) {
        const float* xp = Xf + (size_t)r1 * ldx + kt + sseg;
        float4 f0 = *(const float4*)xp, f1 = *(const float4*)(xp + 4);
        a1.x = packbf(f0.x, f0.y); a1.y = packbf(f0.z, f0.w);
        a1.z = packbf(f1.x, f1.y); a1.w = packbf(f1.z, f1.w);
      }
    }
    uint4 b0 = *(const uint4*)(Wt + (size_t)(bn + srow) * ldw + kt + sseg);
    uint4 b1 = *(const uint4*)(Wt + (size_t)(bn + 64 + srow) * ldw + kt + sseg);
    __syncthreads();
    *(uint4*)(&As[srow][sseg]) = a0;
    *(uint4*)(&As[srow + 64][sseg]) = a1;
    *(uint4*)(&Bs[srow][sseg]) = b0;
    *(uint4*)(&Bs[srow + 64][sseg]) = b1;
    __syncthreads();
    bf16x8 af[4], bfr[4];
#pragma unroll
    for (int i = 0; i < 4; ++i) af[i] = *(const bf16x8*)(&As[wm + i * 16 + lm][lk]);
#pragma unroll
    for (int j = 0; j < 4; ++j) bfr[j] = *(const bf16x8*)(&Bs[wn + j * 16 + lm][lk]);
#pragma unroll
    for (int i = 0; i < 4; ++i)
#pragma unroll
      for (int j = 0; j < 4; ++j)
        acc[i][j] = __builtin_amdgcn_mfma_f32_16x16x32_bf16(af[i], bfr[j], acc[i][j], 0, 0, 0);
  }

  const int qr = quad * 4;
#pragma unroll
  for (int j = 0; j < 4; ++j) {
    int col = bn + wn + j * 16 + lm;
    float bvv = bias ? bias[col] : 0.f;
#pragma unroll
    for (int i = 0; i < 4; ++i) {
      int rbase = bm + wm + i * 16 + qr;
#pragma unroll
      for (int r = 0; r < 4; ++r) {
        int row = rbase + r;
        if (row < M) outB[(size_t)row * 512 + col] = f2bf(acc[i][j][r] + bvv);
      }
    }
  }
}

// ---------------------------------------------------------------------------
// Row-strip MFMA GEMM (R6 version) — IN-PLACE SAFE fallback (BN=512, grid 1-D;
// block reads only its own 64 rows via LDS before the epilogue stores them).
// Used only for SAGE2's Ya GEMM when the workspace lacks a 4th buffer.
// ---------------------------------------------------------------------------
__global__ __launch_bounds__(512) void gemm_strip(
    const void* __restrict__ Xv, int ldx, int K, int xBf16,
    const unsigned short* __restrict__ Wt, int ldw,
    const float* __restrict__ bias,
    unsigned short* __restrict__ outB, int M) {
  __shared__ __align__(16) unsigned short As[64][40];
  const int tid = threadIdx.x;
  const int bm = blockIdx.x * 64;
  const int wv = tid >> 6, lane = tid & 63;
  const int lm = lane & 15, quad = lane >> 4, lk = quad * 8;
  const int cb = wv * 64;
  const int arow = tid >> 3, aseg = (tid & 7) * 4;

  f32x4 zero;
  zero[0] = 0.f; zero[1] = 0.f; zero[2] = 0.f; zero[3] = 0.f;
  f32x4 acc[4][4];
#pragma unroll
  for (int i = 0; i < 4; ++i)
#pragma unroll
    for (int j = 0; j < 4; ++j) acc[i][j] = zero;

  for (int kt = 0; kt < K; kt += 32) {
    uint2 av = make_uint2(0, 0);
    {
      int gr = bm + arow;
      if (gr < M) {
        if (xBf16) {
          av = *(const uint2*)((const unsigned short*)Xv + (size_t)gr * ldx + kt + aseg);
        } else {
          float4 f = *(const float4*)((const float*)Xv + (size_t)gr * ldx + kt + aseg);
          av.x = packbf(f.x, f.y);
          av.y = packbf(f.z, f.w);
        }
      }
    }
    bf16x8 bfr[4];
#pragma unroll
    for (int j = 0; j < 4; ++j)
      bfr[j] = *(const bf16x8*)(Wt + (size_t)(cb + j * 16 + lm) * ldw + kt + lk);
    __syncthreads();
    *(uint2*)(&As[arow][aseg]) = av;
    __syncthreads();
    bf16x8 af[4];
#pragma unroll
    for (int i = 0; i < 4; ++i) af[i] = *(const bf16x8*)(&As[i * 16 + lm][lk]);
#pragma unroll
    for (int i = 0; i < 4; ++i)
#pragma unroll
      for (int j = 0; j < 4; ++j)
        acc[i][j] = __builtin_amdgcn_mfma_f32_16x16x32_bf16(af[i], bfr[j], acc[i][j], 0, 0, 0);
  }

  const int qr = quad * 4;
#pragma unroll
  for (int j = 0; j < 4; ++j) {
    int col = cb + j * 16 + lm;
    float bvv = bias ? bias[col] : 0.f;
#pragma unroll
    for (int i = 0; i < 4; ++i) {
      int rbase = bm + i * 16 + qr;
#pragma unroll
      for (int r = 0; r < 4; ++r) {
        int row = rbase + r;
        if (row < M) outB[(size_t)row * 512 + col] = f2bf(acc[i][j][r] + bvv);
      }
    }
  }
}

// ---------------------------------------------------------------------------
// Fused aggregation + L2 row-norm (one wave per dst node, CSR gather):
//   row = Ya[d] + invdeg[d] * sum_{e in CSR[d]} Yb[esrc[e]];  Ya[d] = row/||row||
// ---------------------------------------------------------------------------
__global__ __launch_bounds__(256) void aggr_norm(
    unsigned short* __restrict__ Ya, const unsigned short* __restrict__ Yb,
    const int* __restrict__ rowptr, const int* __restrict__ esrc,
    const float* __restrict__ invdeg, int M) {
  int d = blockIdx.x * 4 + (threadIdx.x >> 6);
  int lane = threadIdx.x & 63;
  if (d >= M) return;
  float acc[8] = {0.f, 0.f, 0.f, 0.f, 0.f, 0.f, 0.f, 0.f};
  int beg = rowptr[d], end = rowptr[d + 1];
  for (int e = beg; e < end; ++e) {
    int s = esrc[e];
    uint4 u = *(const uint4*)(Yb + (size_t)s * 512 + lane * 8);
    acc[0] += bfLo(u.x); acc[1] += bfHi(u.x);
    acc[2] += bfLo(u.y); acc[3] += bfHi(u.y);
    acc[4] += bfLo(u.z); acc[5] += bfHi(u.z);
    acc[6] += bfLo(u.w); acc[7] += bfHi(u.w);
  }
  float iv = invdeg[d];
  uint4 a = *(const uint4*)(Ya + (size_t)d * 512 + lane * 8);
  float r0 = bfLo(a.x) + iv * acc[0], r1 = bfHi(a.x) + iv * acc[1];
  float r2 = bfLo(a.y) + iv * acc[2], r3 = bfHi(a.y) + iv * acc[3];
  float r4 = bfLo(a.z) + iv * acc[4], r5 = bfHi(a.z) + iv * acc[5];
  float r6 = bfLo(a.w) + iv * acc[6], r7 = bfHi(a.w) + iv * acc[7];
  float ss = r0 * r0 + r1 * r1 + r2 * r2 + r3 * r3
           + r4 * r4 + r5 * r5 + r6 * r6 + r7 * r7;
#pragma unroll
  for (int o = 32; o; o >>= 1) ss += __shfl_xor(ss, o, 64);
  float inv = 1.0f / fmaxf(sqrtf(ss), 1e-12f);
  uint4 o4;
  o4.x = packbf(r0 * inv, r1 * inv);
  o4.y = packbf(r2 * inv, r3 * inv);
  o4.z = packbf(r4 * inv, r5 * inv);
  o4.w = packbf(r6 * inv, r7 * inv);
  *(uint4*)(Ya + (size_t)d * 512 + lane * 8) = o4;
}

// ---------------------------------------------------------------------------
// BN stats over bf16: sums[0..511]=sum, sums[512..1023]=sumsq
// ---------------------------------------------------------------------------
__global__ __launch_bounds__(256) void bn_stats(const unsigned short* __restrict__ T,
                                                int M, float* __restrict__ sums) {
  const int t = threadIdx.x;
  int r0 = blockIdx.x * 128;
  int rend = min(r0 + 128, M);
  float s0 = 0.f, q0 = 0.f, s1 = 0.f, q1 = 0.f;
  for (int r = r0; r < rend; ++r) {
    float a = __uint_as_float((unsigned)T[(size_t)r * 512 + t] << 16);
    float b = __uint_as_float((unsigned)T[(size_t)r * 512 + t + 256] << 16);
    s0 += a; q0 += a * a; s1 += b; q1 += b * b;
  }
  atomicAdd(&sums[t], s0);
  atomicAdd(&sums[t + 256], s1);
  atomicAdd(&sums[512 + t], q0);
  atomicAdd(&sums[512 + t + 256], q1);
}

// BN apply + ReLU (+ optional residual); bf16 in/out, 2 cols per thread.
__global__ __launch_bounds__(256) void bn_apply(const unsigned short* __restrict__ U,
                                                unsigned short* __restrict__ H,
                                                const float* __restrict__ sums,
                                                const float* __restrict__ g,
                                                const float* __restrict__ be,
                                                int M, int residual) {
  size_t i2 = (size_t)blockIdx.x * 256 + threadIdx.x;
  if (i2 >= NS / 2) return;
  int c = ((int)(i2 & 255)) * 2;
  float invM = 1.0f / (float)M;
  float m0 = sums[c] * invM, m1 = sums[c + 1] * invM;
  float v0 = sums[512 + c] * invM - m0 * m0;
  float v1 = sums[512 + c + 1] * invM - m1 * m1;
  float k0 = rsqrtf(v0 + BN_EPS) * g[c], k1 = rsqrtf(v1 + BN_EPS) * g[c + 1];
  unsigned u = ((const unsigned*)U)[i2];
  float x0 = fmaxf((bfLo(u) - m0) * k0 + be[c], 0.f);
  float x1 = fmaxf((bfHi(u) - m1) * k1 + be[c + 1], 0.f);
  if (residual) {
    unsigned hv = ((const unsigned*)H)[i2];
    x0 += bfLo(hv);
    x1 += bfHi(hv);
  }
  ((unsigned*)H)[i2] = packbf(x0, x1);
}

// ---------------------------------------------------------------------------
// Attention pool, sorted-batch segmented version (Watt in registers).
// ---------------------------------------------------------------------------
__global__ __launch_bounds__(256) void att_pool2(const unsigned short* __restrict__ H,
                                                 const int* __restrict__ batch,
                                                 const float* __restrict__ Watt,
                                                 float* __restrict__ hg, int M) {
  __shared__ float fsh[256];
  __shared__ int bsh[256];
  const int tid = threadIdx.x;
  const int base = blockIdx.x * 256;
  bsh[tid] = (base + tid < M) ? batch[base + tid] : -1;
  const int wv = tid >> 6, lane = tid & 63;
  float4 wa0 = *(const float4*)(Watt + lane * 8);
  float4 wa1 = *(const float4*)(Watt + lane * 8 + 4);
  __syncthreads();
  for (int i = wv; i < 256; i += 4) {
    int node = base + i;
    float dot = 0.f;
    if (node < M) {
      uint4 u = *(const uint4*)(H + (size_t)node * 512 + lane * 8);
      dot = bfLo(u.x) * wa0.x + bfHi(u.x) * wa0.y
          + bfLo(u.y) * wa0.z + bfHi(u.y) * wa0.w
          + bfLo(u.z) * wa1.x + bfHi(u.z) * wa1.y
          + bfLo(u.w) * wa1.z + bfHi(u.w) * wa1.w;
    }
#pragma unroll
    for (int o = 32; o; o >>= 1) dot += __shfl_xor(dot, o, 64);
    if (lane == 0) fsh[i] = 0.5f * (1.0f + 1.0f / (1.0f + expf(-dot)));
  }
  __syncthreads();
  float a0 = 0.f, a1 = 0.f;
  int cur = bsh[0];
  for (int i = 0; i < 256; ++i) {
    int node = base + i;
    if (node >= M) break;
    int b = bsh[i];
    if (b != cur) {
      atomicAdd(&hg[(size_t)cur * 512 + tid * 2], a0);
      atomicAdd(&hg[(size_t)cur * 512 + tid * 2 + 1], a1);
      a0 = a1 = 0.f;
      cur = b;
    }
    unsigned u = *(const unsigned*)(H + (size_t)node * 512 + tid * 2);
    float f = fsh[i];
    a0 += bfLo(u) * f;
    a1 += bfHi(u) * f;
  }
  if (cur >= 0) {
    atomicAdd(&hg[(size_t)cur * 512 + tid * 2], a0);
    atomicAdd(&hg[(size_t)cur * 512 + tid * 2 + 1], a1);
  }
}

// ---------------------------------------------------------------------------
// Readout: out[g, n] = (hg[g]/bcnt[g]) . Wread[:, n]
// ---------------------------------------------------------------------------
__global__ __launch_bounds__(256) void readout(const float* __restrict__ hg,
                                               const float* __restrict__ bcnt,
                                               const float* __restrict__ Wr,
                                               float* __restrict__ out) {
  __shared__ float sh[HID];
  int g = blockIdx.x;
  int n = blockIdx.y * 256 + threadIdx.x;
  float inv = 1.0f / fmaxf(bcnt[g], 1.0f);
  for (int k = threadIdx.x; k < HID; k += 256) sh[k] = hg[(size_t)g * HID + k] * inv;
  __syncthreads();
  if (n < NCLS) {
    float acc = 0.f;
    for (int k = 0; k < HID; ++k) acc += sh[k] * Wr[(size_t)k * NCLS + n];
    out[(size_t)g * NCLS + n] = acc;
  }
}

// ---------------------------------------------------------------------------
extern "C" void kernel_launch(void* const* d_in, const int* in_sizes, int n_in,
                              void* d_out, int out_size, void* d_ws, size_t ws_size,
                              hipStream_t stream) {
  const float* x       = (const float*)d_in[0];
  const int*   ei      = (const int*)d_in[1];
  const int*   batch   = (const int*)d_in[2];
  const float* W_embed = (const float*)d_in[3];
  const float* W1      = (const float*)d_in[4];
  const float* b1      = (const float*)d_in[5];
  const float* g1      = (const float*)d_in[6];
  const float* be1     = (const float*)d_in[7];
  const float* W2      = (const float*)d_in[8];
  const float* b2      = (const float*)d_in[9];
  const float* g2      = (const float*)d_in[10];
  const float* be2     = (const float*)d_in[11];
  const float* Watt    = (const float*)d_in[12];
  const float* Wread   = (const float*)d_in[13];
  float* out = (float*)d_out;

  const int* srcIdx = ei;
  const int* dstIdx = ei + N_EDGES;

  char* p = (char*)d_ws;
  unsigned short* B0 = (unsigned short*)p; p += NS * 2;   // h (residual)
  unsigned short* B1 = (unsigned short*)p; p += NS * 2;   // Ya / T
  unsigned short* B2 = (unsigned short*)p; p += NS * 2;   // Yb
  unsigned short* WtE = (unsigned short*)p; p += (size_t)512 * 256 * 2;
  unsigned short* Wt1 = (unsigned short*)p; p += (size_t)3 * 512 * 1024 * 2;
  unsigned short* Wt2 = (unsigned short*)p; p += (size_t)3 * 512 * 1024 * 2;
  float* hg     = (float*)p; p += (size_t)N_GRAPH * HID * 4;
  float* sums   = (float*)p; p += 1024 * 4;
  float* invdeg = (float*)p; p += (size_t)N_NODES * 4;
  float* bcnt   = (float*)p; p += 256;
  int* deg      = (int*)p;   p += (size_t)N_NODES * 4;
  int* fillc    = (int*)p;   p += (size_t)N_NODES * 4;
  int* esrc     = (int*)p;   p += (size_t)N_EDGES * 4;
  int* rowptr   = (int*)p;   p += (size_t)(N_NODES + 1) * 4;
  int* bsum     = (int*)p;   p += (size_t)NB * 4;
  size_t need3 = (size_t)(p - (char*)d_ws);
  if (ws_size < need3) {  // diagnostic sentinel (never expected: R7 fit)
    write_sentinel<<<1, 1, 0, stream>>>(out, (float)need3);
    return;
  }
  // optional 4th activation buffer -> no in-place GEMM at all
  unsigned short* B3 = nullptr;
  if (ws_size >= need3 + NS * 2) B3 = (unsigned short*)((char*)d_ws + need3);

  // ---- weight prep (fp32 -> bf16, transposed [N][K])
  wtrans<<<dim3(8, 16), 256, 0, stream>>>(W_embed, WtE, 256, 512);
  for (int l = 0; l < 3; ++l) {
    wtrans<<<dim3(32, 16), 256, 0, stream>>>(W1 + (size_t)l * 1024 * 512,
                                             Wt1 + (size_t)l * 512 * 1024, 1024, 512);
    wtrans<<<dim3(32, 16), 256, 0, stream>>>(W2 + (size_t)l * 1024 * 512,
                                             Wt2 + (size_t)l * 512 * 1024, 1024, 512);
  }

  // ---- CSR build (parallel scan)
  hipMemsetAsync(deg, 0, N_NODES * sizeof(int), stream);
  hipMemsetAsync(fillc, 0, N_NODES * sizeof(int), stream);
  count_deg<<<(N_EDGES + 255) / 256, 256, 0, stream>>>(dstIdx, deg, N_EDGES);
  make_invdeg<<<(N_NODES + 255) / 256, 256, 0, stream>>>(deg, invdeg, N_NODES);
  scan_part<<<NB, 256, 0, stream>>>(deg, bsum, N_NODES);
  scan_bsums<<<1, 256, 0, stream>>>(bsum, NB);
  scan_final<<<NB, 256, 0, stream>>>(deg, bsum, rowptr, N_NODES);
  fill_csr<<<(N_EDGES + 255) / 256, 256, 0, stream>>>(srcIdx, dstIdx, rowptr, fillc,
                                                      esrc, N_EDGES);

  const dim3 tgrid((N_NODES + 127) / 128, 4);   // tiled GEMM grid
  const int sgrid = (N_NODES + 63) / 64;        // row-strip (fallback)
  const int ngrid = (N_NODES + 3) / 4;
  const int egrid = (int)((NS / 2 + 255) / 256);

  // h = x @ W_embed
  gemm_tiled<<<tgrid, 256, 0, stream>>>(x, 256, 256, 0, WtE, 256, nullptr, B0, N_NODES);

  for (int l = 0; l < 3; ++l) {
    const unsigned short* Wt1l = Wt1 + (size_t)l * 512 * 1024;
    const unsigned short* Wt2l = Wt2 + (size_t)l * 512 * 1024;
    // ---- SAGE 1: B1 = bn(norm(B0@Wa1 + gather(B0@Wb1)))
    gemm_tiled<<<tgrid, 256, 0, stream>>>(B0, 512, 512, 1, Wt1l + 512, 1024,
                                          nullptr, B2, N_NODES);       // Yb
    gemm_tiled<<<tgrid, 256, 0, stream>>>(B0, 512, 512, 1, Wt1l, 1024,
                                          b1 + l * 512, B1, N_NODES);  // Ya
    aggr_norm<<<ngrid, 256, 0, stream>>>(B1, B2, rowptr, esrc, invdeg, N_NODES);
    hipMemsetAsync(sums, 0, 1024 * sizeof(float), stream);
    bn_stats<<<(N_NODES + 127) / 128, 256, 0, stream>>>(B1, N_NODES, sums);
    bn_apply<<<egrid, 256, 0, stream>>>(B1, B1, sums, g1 + l * 512,
                                        be1 + l * 512, N_NODES, 0);
    // ---- SAGE 2 + residual: B0 += relu(bn(norm(B1@Wa2 + gather(B1@Wb2))))
    gemm_tiled<<<tgrid, 256, 0, stream>>>(B1, 512, 512, 1, Wt2l + 512, 1024,
                                          nullptr, B2, N_NODES);       // Yb
    unsigned short* Ya2 = B3 ? B3 : B1;
    if (B3) {
      gemm_tiled<<<tgrid, 256, 0, stream>>>(B1, 512, 512, 1, Wt2l, 1024,
                                            b2 + l * 512, B3, N_NODES);
    } else {
      gemm_strip<<<sgrid, 512, 0, stream>>>(B1, 512, 512, 1, Wt2l, 1024,
                                            b2 + l * 512, B1, N_NODES);  // in-place safe
    }
    aggr_norm<<<ngrid, 256, 0, stream>>>(Ya2, B2, rowptr, esrc, invdeg, N_NODES);
    hipMemsetAsync(sums, 0, 1024 * sizeof(float), stream);
    bn_stats<<<(N_NODES + 127) / 128, 256, 0, stream>>>(Ya2, N_NODES, sums);
    bn_apply<<<egrid, 256, 0, stream>>>(Ya2, B0, sums, g2 + l * 512,
                                        be2 + l * 512, N_NODES, 1);
  }

  // ---- pooling + readout
  hipMemsetAsync(hg, 0, (size_t)N_GRAPH * HID * sizeof(float), stream);
  hipMemsetAsync(bcnt, 0, N_GRAPH * sizeof(float), stream);
  bcount<<<NB, 256, 0, stream>>>(batch, bcnt, N_NODES);
  att_pool2<<<NB, 256, 0, stream>>>(B0, batch, Watt, hg, N_NODES);
  readout<<<dim3(N_GRAPH, 4), 256, 0, stream>>>(hg, bcnt, Wread, out);
}

// Round 10
// 2211.060 us; speedup vs baseline: 1.3283x; 1.0485x over previous
//
#include <hip/hip_runtime.h>
#include <math.h>

#define N_NODES 60000
#define N_EDGES 360000
#define N_GRAPH 64
#define HID 512
#define NCLS 1000
#define BN_EPS 1e-5f
#define NS ((size_t)N_NODES * HID)
#define NB 235  // (N_NODES + 255) / 256

typedef __bf16 bf16x8 __attribute__((ext_vector_type(8)));
typedef float f32x4 __attribute__((ext_vector_type(4)));

static __device__ __forceinline__ unsigned short f2bf(float f) {
  unsigned u = __float_as_uint(f);
  unsigned r = (u + 0x7fffu + ((u >> 16) & 1u)) >> 16;  // RNE
  return (unsigned short)r;
}
static __device__ __forceinline__ float bfLo(unsigned u) { return __uint_as_float(u << 16); }
static __device__ __forceinline__ float bfHi(unsigned u) { return __uint_as_float(u & 0xffff0000u); }
static __device__ __forceinline__ unsigned packbf(float a, float b) {
  return (unsigned)f2bf(a) | ((unsigned)f2bf(b) << 16);
}

__global__ void write_sentinel(float* out, float v) { out[0] = v; }

// ---------------------------------------------------------------------------
// Weight fp32 -> bf16 transpose: Wt[n][k] = bf16(W[k][n]).  32x32 tiles.
// ---------------------------------------------------------------------------
__global__ __launch_bounds__(256) void wtrans(const float* __restrict__ W,
                                              unsigned short* __restrict__ Wt,
                                              int K, int N) {
  __shared__ float sh[32][33];
  int kt = blockIdx.x * 32, nt = blockIdx.y * 32;
  int tx = threadIdx.x & 31, ty = threadIdx.x >> 5;  // ty 0..7
#pragma unroll
  for (int i = 0; i < 4; ++i)
    sh[ty + i * 8][tx] = W[(size_t)(kt + ty + i * 8) * N + nt + tx];
  __syncthreads();
#pragma unroll
  for (int i = 0; i < 4; ++i)
    Wt[(size_t)(nt + ty + i * 8) * K + kt + tx] = f2bf(sh[tx][ty + i * 8]);
}

// ---------------------------------------------------------------------------
// Degree / CSR build
// ---------------------------------------------------------------------------
__global__ __launch_bounds__(256) void count_deg(const int* __restrict__ dst,
                                                 int* __restrict__ deg, int E) {
  int e = blockIdx.x * 256 + threadIdx.x;
  if (e < E) atomicAdd(&deg[dst[e]], 1);
}

__global__ __launch_bounds__(256) void make_invdeg(const int* __restrict__ deg,
                                                   float* __restrict__ inv, int n) {
  int i = blockIdx.x * 256 + threadIdx.x;
  if (i < n) inv[i] = 1.0f / fmaxf((float)deg[i], 1.0f);
}

// ---- parallel 3-phase exclusive scan of deg -> rowptr -----------------------
__global__ __launch_bounds__(256) void scan_part(const int* __restrict__ deg,
                                                 int* __restrict__ bsum, int n) {
  __shared__ int sh[256];
  int i = blockIdx.x * 256 + threadIdx.x;
  sh[threadIdx.x] = (i < n) ? deg[i] : 0;
  __syncthreads();
  for (int off = 128; off; off >>= 1) {
    if (threadIdx.x < off) sh[threadIdx.x] += sh[threadIdx.x + off];
    __syncthreads();
  }
  if (threadIdx.x == 0) bsum[blockIdx.x] = sh[0];
}

__global__ __launch_bounds__(256) void scan_bsums(int* __restrict__ bsum, int nb) {
  __shared__ int sh[256];
  int t = threadIdx.x;
  int v = (t < nb) ? bsum[t] : 0;
  sh[t] = v;
  __syncthreads();
  for (int off = 1; off < 256; off <<= 1) {
    int u = (t >= off) ? sh[t - off] : 0;
    __syncthreads();
    sh[t] += u;
    __syncthreads();
  }
  if (t < nb) bsum[t] = sh[t] - v;  // exclusive
}

__global__ __launch_bounds__(256) void scan_final(const int* __restrict__ deg,
                                                  const int* __restrict__ bsum,
                                                  int* __restrict__ rowptr, int n) {
  __shared__ int sh[256];
  int t = threadIdx.x;
  int i = blockIdx.x * 256 + t;
  int v = (i < n) ? deg[i] : 0;
  sh[t] = v;
  __syncthreads();
  for (int off = 1; off < 256; off <<= 1) {
    int u = (t >= off) ? sh[t - off] : 0;
    __syncthreads();
    sh[t] += u;
    __syncthreads();
  }
  if (i < n) rowptr[i + 1] = bsum[blockIdx.x] + sh[t];
  if (i == 0) rowptr[0] = 0;
}

__global__ __launch_bounds__(256) void fill_csr(const int* __restrict__ src,
                                                const int* __restrict__ dst,
                                                const int* __restrict__ rowptr,
                                                int* __restrict__ fillc,
                                                int* __restrict__ esrc, int E) {
  int e = blockIdx.x * 256 + threadIdx.x;
  if (e < E) {
    int d = dst[e];
    int pos = rowptr[d] + atomicAdd(&fillc[d], 1);
    esrc[pos] = src[e];
  }
}

// LDS-histogram batch count
__global__ __launch_bounds__(256) void bcount(const int* __restrict__ batch,
                                              float* __restrict__ bcnt, int n) {
  __shared__ int h[N_GRAPH];
  if (threadIdx.x < N_GRAPH) h[threadIdx.x] = 0;
  __syncthreads();
  int i = blockIdx.x * 256 + threadIdx.x;
  if (i < n) atomicAdd(&h[batch[i]], 1);
  __syncthreads();
  if (threadIdx.x < N_GRAPH && h[threadIdx.x])
    atomicAdd(&bcnt[threadIdx.x], (float)h[threadIdx.x]);
}

// ---------------------------------------------------------------------------
// gemm_glds (m97 structure): out[M x 512](bf16) = X[M x 512]bf16 @ W (+ bias)
// Wt = W^T bf16 [512][ldw]. 128x128 tile, BK=32, 256 thr = 4 waves (2x2).
// A/B tiles staged with __builtin_amdgcn_global_load_lds width=16 into
// UNPADDED LDS [128][32] (glds lands at wave-uniform base + lane*16: offset
// (lane>>2)*32+(lane&3)*8 halfs == lane*8 halfs -- exact match).
// OOB A-row reads (last strip) land in the adjacent ws buffer: harmless,
// stores are guarded.  NOT in-place safe (grid.y = 4).
// ---------------------------------------------------------------------------
__global__ __launch_bounds__(256) void gemm_glds(
    const unsigned short* __restrict__ Xb, int ldx,
    const unsigned short* __restrict__ Wt, int ldw,
    const float* __restrict__ bias,
    unsigned short* __restrict__ outB, int M) {
  __shared__ __align__(16) unsigned short As[128 * 32];
  __shared__ __align__(16) unsigned short Bs[128 * 32];
  const int tid = threadIdx.x;
  const int bm = blockIdx.x * 128;
  const int bn = blockIdx.y * 128;
  const int wv = tid >> 6, lane = tid & 63;
  const int wm = (wv >> 1) * 64, wn = (wv & 1) * 64;
  const int lm = lane & 15, quad = lane >> 4;
  const int crow = lane >> 2, cseg = (lane & 3) * 8;  // within-chunk row/seg

  f32x4 zero;
  zero[0] = 0.f; zero[1] = 0.f; zero[2] = 0.f; zero[3] = 0.f;
  f32x4 acc[4][4];
#pragma unroll
  for (int i = 0; i < 4; ++i)
#pragma unroll
    for (int j = 0; j < 4; ++j) acc[i][j] = zero;

  for (int kt = 0; kt < 512; kt += 32) {
    __syncthreads();  // previous ds_reads complete before LDS overwrite
#pragma unroll
    for (int r = 0; r < 2; ++r) {
      int chunk = wv + r * 4;           // 0..7, wave-uniform
      int row = chunk * 16 + crow;      // tile row 0..127
      const unsigned short* ga = Xb + (size_t)(bm + row) * ldx + kt + cseg;
      const unsigned short* gb = Wt + (size_t)(bn + row) * ldw + kt + cseg;
      __builtin_amdgcn_global_load_lds(
          (const __attribute__((address_space(1))) unsigned int*)ga,
          (__attribute__((address_space(3))) unsigned int*)(As + chunk * 512),
          16, 0, 0);
      __builtin_amdgcn_global_load_lds(
          (const __attribute__((address_space(1))) unsigned int*)gb,
          (__attribute__((address_space(3))) unsigned int*)(Bs + chunk * 512),
          16, 0, 0);
    }
    __syncthreads();  // drains vmcnt: staged data visible
    bf16x8 af[4], bfr[4];
#pragma unroll
    for (int i = 0; i < 4; ++i)
      af[i] = *(const bf16x8*)(As + (wm + i * 16 + lm) * 32 + quad * 8);
#pragma unroll
    for (int j = 0; j < 4; ++j)
      bfr[j] = *(const bf16x8*)(Bs + (wn + j * 16 + lm) * 32 + quad * 8);
#pragma unroll
    for (int i = 0; i < 4; ++i)
#pragma unroll
      for (int j = 0; j < 4; ++j)
        acc[i][j] = __builtin_amdgcn_mfma_f32_16x16x32_bf16(af[i], bfr[j], acc[i][j], 0, 0, 0);
  }

  const int qr = quad * 4;
#pragma unroll
  for (int j = 0; j < 4; ++j) {
    int col = bn + wn + j * 16 + lm;
    float bvv = bias ? bias[col] : 0.f;
#pragma unroll
    for (int i = 0; i < 4; ++i) {
      int rbase = bm + wm + i * 16 + qr;
#pragma unroll
      for (int r = 0; r < 4; ++r) {
        int row = rbase + r;
        if (row < M) outB[(size_t)row * 512 + col] = f2bf(acc[i][j][r] + bvv);
      }
    }
  }
}

// ---------------------------------------------------------------------------
// Tiled MFMA GEMM (m93 structure) — fp32-input path (embed GEMM only).
// ---------------------------------------------------------------------------
__global__ __launch_bounds__(256) void gemm_tiled(
    const float* __restrict__ Xf, int ldx, int K,
    const unsigned short* __restrict__ Wt, int ldw,
    const float* __restrict__ bias,
    unsigned short* __restrict__ outB, int M) {
  __shared__ __align__(16) unsigned short As[128][40];
  __shared__ __align__(16) unsigned short Bs[128][40];
  const int tid = threadIdx.x;
  const int bm = blockIdx.x * 128;
  const int bn = blockIdx.y * 128;
  const int wv = tid >> 6, lane = tid & 63;
  const int wm = (wv >> 1) * 64, wn = (wv & 1) * 64;
  const int lm = lane & 15, quad = lane >> 4, lk = quad * 8;
  const int srow = tid >> 2, sseg = (tid & 3) * 8;

  f32x4 zero;
  zero[0] = 0.f; zero[1] = 0.f; zero[2] = 0.f; zero[3] = 0.f;
  f32x4 acc[4][4];
#pragma unroll
  for (int i = 0; i < 4; ++i)
#pragma unroll
    for (int j = 0; j < 4; ++j) acc[i][j] = zero;

  const int r0 = bm + srow, r1 = bm + 64 + srow;
  for (int kt = 0; kt < K; kt += 32) {
    uint4 a0 = make_uint4(0, 0, 0, 0), a1 = make_uint4(0, 0, 0, 0);
    if (r0 < M) {
      const float* xp = Xf + (size_t)r0 * ldx + kt + sseg;
      float4 f0 = *(const float4*)xp, f1 = *(const float4*)(xp + 4);
      a0.x = packbf(f0.x, f0.y); a0.y = packbf(f0.z, f0.w);
      a0.z = packbf(f1.x, f1.y); a0.w = packbf(f1.z, f1.w);
    }
    if (r1 < M) {
      const float* xp = Xf + (size_t)r1 * ldx + kt + sseg;
      float4 f0 = *(const float4*)xp, f1 = *(const float4*)(xp + 4);
      a1.x = packbf(f0.x, f0.y); a1.y = packbf(f0.z, f0.w);
      a1.z = packbf(f1.x, f1.y); a1.w = packbf(f1.z, f1.w);
    }
    uint4 b0 = *(const uint4*)(Wt + (size_t)(bn + srow) * ldw + kt + sseg);
    uint4 b1 = *(const uint4*)(Wt + (size_t)(bn + 64 + srow) * ldw + kt + sseg);
    __syncthreads();
    *(uint4*)(&As[srow][sseg]) = a0;
    *(uint4*)(&As[srow + 64][sseg]) = a1;
    *(uint4*)(&Bs[srow][sseg]) = b0;
    *(uint4*)(&Bs[srow + 64][sseg]) = b1;
    __syncthreads();
    bf16x8 af[4], bfr[4];
#pragma unroll
    for (int i = 0; i < 4; ++i) af[i] = *(const bf16x8*)(&As[wm + i * 16 + lm][lk]);
#pragma unroll
    for (int j = 0; j < 4; ++j) bfr[j] = *(const bf16x8*)(&Bs[wn + j * 16 + lm][lk]);
#pragma unroll
    for (int i = 0; i < 4; ++i)
#pragma unroll
      for (int j = 0; j < 4; ++j)
        acc[i][j] = __builtin_amdgcn_mfma_f32_16x16x32_bf16(af[i], bfr[j], acc[i][j], 0, 0, 0);
  }

  const int qr = quad * 4;
#pragma unroll
  for (int j = 0; j < 4; ++j) {
    int col = bn + wn + j * 16 + lm;
    float bvv = bias ? bias[col] : 0.f;
#pragma unroll
    for (int i = 0; i < 4; ++i) {
      int rbase = bm + wm + i * 16 + qr;
#pragma unroll
      for (int r = 0; r < 4; ++r) {
        int row = rbase + r;
        if (row < M) outB[(size_t)row * 512 + col] = f2bf(acc[i][j][r] + bvv);
      }
    }
  }
}

// ---------------------------------------------------------------------------
// Row-strip MFMA GEMM — IN-PLACE SAFE fallback (used only if ws lacks B3).
// ---------------------------------------------------------------------------
__global__ __launch_bounds__(512) void gemm_strip(
    const unsigned short* __restrict__ Xb, int ldx,
    const unsigned short* __restrict__ Wt, int ldw,
    const float* __restrict__ bias,
    unsigned short* __restrict__ outB, int M) {
  __shared__ __align__(16) unsigned short As[64][40];
  const int tid = threadIdx.x;
  const int bm = blockIdx.x * 64;
  const int wv = tid >> 6, lane = tid & 63;
  const int lm = lane & 15, quad = lane >> 4, lk = quad * 8;
  const int cb = wv * 64;
  const int arow = tid >> 3, aseg = (tid & 7) * 4;

  f32x4 zero;
  zero[0] = 0.f; zero[1] = 0.f; zero[2] = 0.f; zero[3] = 0.f;
  f32x4 acc[4][4];
#pragma unroll
  for (int i = 0; i < 4; ++i)
#pragma unroll
    for (int j = 0; j < 4; ++j) acc[i][j] = zero;

  for (int kt = 0; kt < 512; kt += 32) {
    uint2 av = make_uint2(0, 0);
    int gr = bm + arow;
    if (gr < M) av = *(const uint2*)(Xb + (size_t)gr * ldx + kt + aseg);
    bf16x8 bfr[4];
#pragma unroll
    for (int j = 0; j < 4; ++j)
      bfr[j] = *(const bf16x8*)(Wt + (size_t)(cb + j * 16 + lm) * ldw + kt + lk);
    __syncthreads();
    *(uint2*)(&As[arow][aseg]) = av;
    __syncthreads();
    bf16x8 af[4];
#pragma unroll
    for (int i = 0; i < 4; ++i) af[i] = *(const bf16x8*)(&As[i * 16 + lm][lk]);
#pragma unroll
    for (int i = 0; i < 4; ++i)
#pragma unroll
      for (int j = 0; j < 4; ++j)
        acc[i][j] = __builtin_amdgcn_mfma_f32_16x16x32_bf16(af[i], bfr[j], acc[i][j], 0, 0, 0);
  }

  const int qr = quad * 4;
#pragma unroll
  for (int j = 0; j < 4; ++j) {
    int col = cb + j * 16 + lm;
    float bvv = bias ? bias[col] : 0.f;
#pragma unroll
    for (int i = 0; i < 4; ++i) {
      int rbase = bm + i * 16 + qr;
#pragma unroll
      for (int r = 0; r < 4; ++r) {
        int row = rbase + r;
        if (row < M) outB[(size_t)row * 512 + col] = f2bf(acc[i][j][r] + bvv);
      }
    }
  }
}

// ---------------------------------------------------------------------------
// Fused aggregation + L2 row-norm (one wave per dst node, CSR gather)
// ---------------------------------------------------------------------------
__global__ __launch_bounds__(256) void aggr_norm(
    unsigned short* __restrict__ Ya, const unsigned short* __restrict__ Yb,
    const int* __restrict__ rowptr, const int* __restrict__ esrc,
    const float* __restrict__ invdeg, int M) {
  int d = blockIdx.x * 4 + (threadIdx.x >> 6);
  int lane = threadIdx.x & 63;
  if (d >= M) return;
  float acc[8] = {0.f, 0.f, 0.f, 0.f, 0.f, 0.f, 0.f, 0.f};
  int beg = rowptr[d], end = rowptr[d + 1];
  for (int e = beg; e < end; ++e) {
    int s = esrc[e];
    uint4 u = *(const uint4*)(Yb + (size_t)s * 512 + lane * 8);
    acc[0] += bfLo(u.x); acc[1] += bfHi(u.x);
    acc[2] += bfLo(u.y); acc[3] += bfHi(u.y);
    acc[4] += bfLo(u.z); acc[5] += bfHi(u.z);
    acc[6] += bfLo(u.w); acc[7] += bfHi(u.w);
  }
  float iv = invdeg[d];
  uint4 a = *(const uint4*)(Ya + (size_t)d * 512 + lane * 8);
  float r0 = bfLo(a.x) + iv * acc[0], r1 = bfHi(a.x) + iv * acc[1];
  float r2 = bfLo(a.y) + iv * acc[2], r3 = bfHi(a.y) + iv * acc[3];
  float r4 = bfLo(a.z) + iv * acc[4], r5 = bfHi(a.z) + iv * acc[5];
  float r6 = bfLo(a.w) + iv * acc[6], r7 = bfHi(a.w) + iv * acc[7];
  float ss = r0 * r0 + r1 * r1 + r2 * r2 + r3 * r3
           + r4 * r4 + r5 * r5 + r6 * r6 + r7 * r7;
#pragma unroll
  for (int o = 32; o; o >>= 1) ss += __shfl_xor(ss, o, 64);
  float inv = 1.0f / fmaxf(sqrtf(ss), 1e-12f);
  uint4 o4;
  o4.x = packbf(r0 * inv, r1 * inv);
  o4.y = packbf(r2 * inv, r3 * inv);
  o4.z = packbf(r4 * inv, r5 * inv);
  o4.w = packbf(r6 * inv, r7 * inv);
  *(uint4*)(Ya + (size_t)d * 512 + lane * 8) = o4;
}

// ---------------------------------------------------------------------------
// BN stats over bf16: sums[0..511]=sum, sums[512..1023]=sumsq
// ---------------------------------------------------------------------------
__global__ __launch_bounds__(256) void bn_stats(const unsigned short* __restrict__ T,
                                                int M, float* __restrict__ sums) {
  const int t = threadIdx.x;
  int r0 = blockIdx.x * 128;
  int rend = min(r0 + 128, M);
  float s0 = 0.f, q0 = 0.f, s1 = 0.f, q1 = 0.f;
  for (int r = r0; r < rend; ++r) {
    float a = __uint_as_float((unsigned)T[(size_t)r * 512 + t] << 16);
    float b = __uint_as_float((unsigned)T[(size_t)r * 512 + t + 256] << 16);
    s0 += a; q0 += a * a; s1 += b; q1 += b * b;
  }
  atomicAdd(&sums[t], s0);
  atomicAdd(&sums[t + 256], s1);
  atomicAdd(&sums[512 + t], q0);
  atomicAdd(&sums[512 + t + 256], q1);
}

// BN apply + ReLU (+ optional residual); bf16 in/out, 2 cols per thread.
__global__ __launch_bounds__(256) void bn_apply(const unsigned short* __restrict__ U,
                                                unsigned short* __restrict__ H,
                                                const float* __restrict__ sums,
                                                const float* __restrict__ g,
                                                const float* __restrict__ be,
                                                int M, int residual) {
  size_t i2 = (size_t)blockIdx.x * 256 + threadIdx.x;
  if (i2 >= NS / 2) return;
  int c = ((int)(i2 & 255)) * 2;
  float invM = 1.0f / (float)M;
  float m0 = sums[c] * invM, m1 = sums[c + 1] * invM;
  float v0 = sums[512 + c] * invM - m0 * m0;
  float v1 = sums[512 + c + 1] * invM - m1 * m1;
  float k0 = rsqrtf(v0 + BN_EPS) * g[c], k1 = rsqrtf(v1 + BN_EPS) * g[c + 1];
  unsigned u = ((const unsigned*)U)[i2];
  float x0 = fmaxf((bfLo(u) - m0) * k0 + be[c], 0.f);
  float x1 = fmaxf((bfHi(u) - m1) * k1 + be[c + 1], 0.f);
  if (residual) {
    unsigned hv = ((const unsigned*)H)[i2];
    x0 += bfLo(hv);
    x1 += bfHi(hv);
  }
  ((unsigned*)H)[i2] = packbf(x0, x1);
}

// ---------------------------------------------------------------------------
// Attention pool, sorted-batch segmented, 64 nodes/block (938 blocks).
// ---------------------------------------------------------------------------
#define NPB 64
__global__ __launch_bounds__(256) void att_pool2(const unsigned short* __restrict__ H,
                                                 const int* __restrict__ batch,
                                                 const float* __restrict__ Watt,
                                                 float* __restrict__ hg, int M) {
  __shared__ float fsh[NPB];
  __shared__ int bsh[NPB];
  const int tid = threadIdx.x;
  const int base = blockIdx.x * NPB;
  if (tid < NPB) bsh[tid] = (base + tid < M) ? batch[base + tid] : -1;
  const int wv = tid >> 6, lane = tid & 63;
  float4 wa0 = *(const float4*)(Watt + lane * 8);
  float4 wa1 = *(const float4*)(Watt + lane * 8 + 4);
  __syncthreads();
  for (int i = wv; i < NPB; i += 4) {
    int node = base + i;
    float dot = 0.f;
    if (node < M) {
      uint4 u = *(const uint4*)(H + (size_t)node * 512 + lane * 8);
      dot = bfLo(u.x) * wa0.x + bfHi(u.x) * wa0.y
          + bfLo(u.y) * wa0.z + bfHi(u.y) * wa0.w
          + bfLo(u.z) * wa1.x + bfHi(u.z) * wa1.y
          + bfLo(u.w) * wa1.z + bfHi(u.w) * wa1.w;
    }
#pragma unroll
    for (int o = 32; o; o >>= 1) dot += __shfl_xor(dot, o, 64);
    if (lane == 0) fsh[i] = 0.5f * (1.0f + 1.0f / (1.0f + expf(-dot)));
  }
  __syncthreads();
  float a0 = 0.f, a1 = 0.f;
  int cur = bsh[0];
  for (int i = 0; i < NPB; ++i) {
    int node = base + i;
    if (node >= M) break;
    int b = bsh[i];
    if (b != cur) {
      atomicAdd(&hg[(size_t)cur * 512 + tid * 2], a0);
      atomicAdd(&hg[(size_t)cur * 512 + tid * 2 + 1], a1);
      a0 = a1 = 0.f;
      cur = b;
    }
    unsigned u = *(const unsigned*)(H + (size_t)node * 512 + tid * 2);
    float f = fsh[i];
    a0 += bfLo(u) * f;
    a1 += bfHi(u) * f;
  }
  if (cur >= 0) {
    atomicAdd(&hg[(size_t)cur * 512 + tid * 2], a0);
    atomicAdd(&hg[(size_t)cur * 512 + tid * 2 + 1], a1);
  }
}

// ---------------------------------------------------------------------------
// Readout: out[g, n] = (hg[g]/bcnt[g]) . Wread[:, n]
// ---------------------------------------------------------------------------
__global__ __launch_bounds__(256) void readout(const float* __restrict__ hg,
                                               const float* __restrict__ bcnt,
                                               const float* __restrict__ Wr,
                                               float* __restrict__ out) {
  __shared__ float sh[HID];
  int g = blockIdx.x;
  int n = blockIdx.y * 256 + threadIdx.x;
  float inv = 1.0f / fmaxf(bcnt[g], 1.0f);
  for (int k = threadIdx.x; k < HID; k += 256) sh[k] = hg[(size_t)g * HID + k] * inv;
  __syncthreads();
  if (n < NCLS) {
    float acc = 0.f;
    for (int k = 0; k < HID; ++k) acc += sh[k] * Wr[(size_t)k * NCLS + n];
    out[(size_t)g * NCLS + n] = acc;
  }
}

// ---------------------------------------------------------------------------
extern "C" void kernel_launch(void* const* d_in, const int* in_sizes, int n_in,
                              void* d_out, int out_size, void* d_ws, size_t ws_size,
                              hipStream_t stream) {
  const float* x       = (const float*)d_in[0];
  const int*   ei      = (const int*)d_in[1];
  const int*   batch   = (const int*)d_in[2];
  const float* W_embed = (const float*)d_in[3];
  const float* W1      = (const float*)d_in[4];
  const float* b1      = (const float*)d_in[5];
  const float* g1      = (const float*)d_in[6];
  const float* be1     = (const float*)d_in[7];
  const float* W2      = (const float*)d_in[8];
  const float* b2      = (const float*)d_in[9];
  const float* g2      = (const float*)d_in[10];
  const float* be2     = (const float*)d_in[11];
  const float* Watt    = (const float*)d_in[12];
  const float* Wread   = (const float*)d_in[13];
  float* out = (float*)d_out;

  const int* srcIdx = ei;
  const int* dstIdx = ei + N_EDGES;

  char* p = (char*)d_ws;
  unsigned short* B0 = (unsigned short*)p; p += NS * 2;   // h (residual)
  unsigned short* B1 = (unsigned short*)p; p += NS * 2;   // Ya / T
  unsigned short* B2 = (unsigned short*)p; p += NS * 2;   // Yb
  unsigned short* WtE = (unsigned short*)p; p += (size_t)512 * 256 * 2;
  unsigned short* Wt1 = (unsigned short*)p; p += (size_t)3 * 512 * 1024 * 2;
  unsigned short* Wt2 = (unsigned short*)p; p += (size_t)3 * 512 * 1024 * 2;
  float* hg     = (float*)p; p += (size_t)N_GRAPH * HID * 4;
  float* sums   = (float*)p; p += 1024 * 4;
  float* invdeg = (float*)p; p += (size_t)N_NODES * 4;
  float* bcnt   = (float*)p; p += 256;
  int* deg      = (int*)p;   p += (size_t)N_NODES * 4;
  int* fillc    = (int*)p;   p += (size_t)N_NODES * 4;
  int* esrc     = (int*)p;   p += (size_t)N_EDGES * 4;
  int* rowptr   = (int*)p;   p += (size_t)(N_NODES + 1) * 4;
  int* bsum     = (int*)p;   p += (size_t)NB * 4;
  size_t need3 = (size_t)(p - (char*)d_ws);
  if (ws_size < need3) {
    write_sentinel<<<1, 1, 0, stream>>>(out, (float)need3);
    return;
  }
  // optional 4th activation buffer -> no in-place GEMM at all
  unsigned short* B3 = nullptr;
  if (ws_size >= need3 + NS * 2) B3 = (unsigned short*)((char*)d_ws + need3);

  // ---- weight prep (fp32 -> bf16, transposed [N][K])
  wtrans<<<dim3(8, 16), 256, 0, stream>>>(W_embed, WtE, 256, 512);
  for (int l = 0; l < 3; ++l) {
    wtrans<<<dim3(32, 16), 256, 0, stream>>>(W1 + (size_t)l * 1024 * 512,
                                             Wt1 + (size_t)l * 512 * 1024, 1024, 512);
    wtrans<<<dim3(32, 16), 256, 0, stream>>>(W2 + (size_t)l * 1024 * 512,
                                             Wt2 + (size_t)l * 512 * 1024, 1024, 512);
  }

  // ---- CSR build (parallel scan)
  hipMemsetAsync(deg, 0, N_NODES * sizeof(int), stream);
  hipMemsetAsync(fillc, 0, N_NODES * sizeof(int), stream);
  count_deg<<<(N_EDGES + 255) / 256, 256, 0, stream>>>(dstIdx, deg, N_EDGES);
  make_invdeg<<<(N_NODES + 255) / 256, 256, 0, stream>>>(deg, invdeg, N_NODES);
  scan_part<<<NB, 256, 0, stream>>>(deg, bsum, N_NODES);
  scan_bsums<<<1, 256, 0, stream>>>(bsum, NB);
  scan_final<<<NB, 256, 0, stream>>>(deg, bsum, rowptr, N_NODES);
  fill_csr<<<(N_EDGES + 255) / 256, 256, 0, stream>>>(srcIdx, dstIdx, rowptr, fillc,
                                                      esrc, N_EDGES);

  const dim3 tgrid((N_NODES + 127) / 128, 4);
  const int sgrid = (N_NODES + 63) / 64;
  const int ngrid = (N_NODES + 3) / 4;
  const int egrid = (int)((NS / 2 + 255) / 256);

  // h = x @ W_embed (fp32 input -> staging-convert path)
  gemm_tiled<<<tgrid, 256, 0, stream>>>(x, 256, 256, WtE, 256, nullptr, B0, N_NODES);

  for (int l = 0; l < 3; ++l) {
    const unsigned short* Wt1l = Wt1 + (size_t)l * 512 * 1024;
    const unsigned short* Wt2l = Wt2 + (size_t)l * 512 * 1024;
    // ---- SAGE 1: B1 = bn(norm(B0@Wa1 + gather(B0@Wb1)))
    gemm_glds<<<tgrid, 256, 0, stream>>>(B0, 512, Wt1l + 512, 1024,
                                         nullptr, B2, N_NODES);        // Yb
    gemm_glds<<<tgrid, 256, 0, stream>>>(B0, 512, Wt1l, 1024,
                                         b1 + l * 512, B1, N_NODES);   // Ya
    aggr_norm<<<ngrid, 256, 0, stream>>>(B1, B2, rowptr, esrc, invdeg, N_NODES);
    hipMemsetAsync(sums, 0, 1024 * sizeof(float), stream);
    bn_stats<<<(N_NODES + 127) / 128, 256, 0, stream>>>(B1, N_NODES, sums);
    bn_apply<<<egrid, 256, 0, stream>>>(B1, B1, sums, g1 + l * 512,
                                        be1 + l * 512, N_NODES, 0);
    // ---- SAGE 2 + residual: B0 += relu(bn(norm(B1@Wa2 + gather(B1@Wb2))))
    gemm_glds<<<tgrid, 256, 0, stream>>>(B1, 512, Wt2l + 512, 1024,
                                         nullptr, B2, N_NODES);        // Yb
    unsigned short* Ya2 = B3 ? B3 : B1;
    if (B3) {
      gemm_glds<<<tgrid, 256, 0, stream>>>(B1, 512, Wt2l, 1024,
                                           b2 + l * 512, B3, N_NODES);
    } else {
      gemm_strip<<<sgrid, 512, 0, stream>>>(B1, 512, Wt2l, 1024,
                                            b2 + l * 512, B1, N_NODES);  // in-place safe
    }
    aggr_norm<<<ngrid, 256, 0, stream>>>(Ya2, B2, rowptr, esrc, invdeg, N_NODES);
    hipMemsetAsync(sums, 0, 1024 * sizeof(float), stream);
    bn_stats<<<(N_NODES + 127) / 128, 256, 0, stream>>>(Ya2, N_NODES, sums);
    bn_apply<<<egrid, 256, 0, stream>>>(Ya2, B0, sums, g2 + l * 512,
                                        be2 + l * 512, N_NODES, 1);
  }

  // ---- pooling + readout
  hipMemsetAsync(hg, 0, (size_t)N_GRAPH * HID * sizeof(float), stream);
  hipMemsetAsync(bcnt, 0, N_GRAPH * sizeof(float), stream);
  bcount<<<NB, 256, 0, stream>>>(batch, bcnt, N_NODES);
  att_pool2<<<(N_NODES + NPB - 1) / NPB, 256, 0, stream>>>(B0, batch, Watt, hg, N_NODES);
  readout<<<dim3(N_GRAPH, 4), 256, 0, stream>>>(hg, bcnt, Wread, out);
}

// Round 11
// 2086.808 us; speedup vs baseline: 1.4074x; 1.0595x over previous
//
#include <hip/hip_runtime.h>
#include <math.h>

#define N_NODES 60000
#define N_EDGES 360000
#define N_GRAPH 64
#define HID 512
#define NCLS 1000
#define BN_EPS 1e-5f
#define NS ((size_t)N_NODES * HID)
#define NB 235      // (N_NODES + 255) / 256
#define STRIPS 469  // ceil(60000/128)

typedef __bf16 bf16x8 __attribute__((ext_vector_type(8)));
typedef float f32x4 __attribute__((ext_vector_type(4)));

static __device__ __forceinline__ unsigned short f2bf(float f) {
  unsigned u = __float_as_uint(f);
  unsigned r = (u + 0x7fffu + ((u >> 16) & 1u)) >> 16;  // RNE
  return (unsigned short)r;
}
static __device__ __forceinline__ float bfLo(unsigned u) { return __uint_as_float(u << 16); }
static __device__ __forceinline__ float bfHi(unsigned u) { return __uint_as_float(u & 0xffff0000u); }
static __device__ __forceinline__ unsigned packbf(float a, float b) {
  return (unsigned)f2bf(a) | ((unsigned)f2bf(b) << 16);
}

__global__ void write_sentinel(float* out, float v) { out[0] = v; }

// ---------------------------------------------------------------------------
// Weight fp32 -> bf16 transpose: Wt[n][k] = bf16(W[k][n]).  32x32 tiles.
// ---------------------------------------------------------------------------
__global__ __launch_bounds__(256) void wtrans(const float* __restrict__ W,
                                              unsigned short* __restrict__ Wt,
                                              int K, int N) {
  __shared__ float sh[32][33];
  int kt = blockIdx.x * 32, nt = blockIdx.y * 32;
  int tx = threadIdx.x & 31, ty = threadIdx.x >> 5;  // ty 0..7
#pragma unroll
  for (int i = 0; i < 4; ++i)
    sh[ty + i * 8][tx] = W[(size_t)(kt + ty + i * 8) * N + nt + tx];
  __syncthreads();
#pragma unroll
  for (int i = 0; i < 4; ++i)
    Wt[(size_t)(nt + ty + i * 8) * K + kt + tx] = f2bf(sh[tx][ty + i * 8]);
}

// ---------------------------------------------------------------------------
// Degree / CSR build
// ---------------------------------------------------------------------------
__global__ __launch_bounds__(256) void count_deg(const int* __restrict__ dst,
                                                 int* __restrict__ deg, int E) {
  int e = blockIdx.x * 256 + threadIdx.x;
  if (e < E) atomicAdd(&deg[dst[e]], 1);
}

__global__ __launch_bounds__(256) void make_invdeg(const int* __restrict__ deg,
                                                   float* __restrict__ inv, int n) {
  int i = blockIdx.x * 256 + threadIdx.x;
  if (i < n) inv[i] = 1.0f / fmaxf((float)deg[i], 1.0f);
}

// ---- parallel 3-phase exclusive scan of deg -> rowptr -----------------------
__global__ __launch_bounds__(256) void scan_part(const int* __restrict__ deg,
                                                 int* __restrict__ bsum, int n) {
  __shared__ int sh[256];
  int i = blockIdx.x * 256 + threadIdx.x;
  sh[threadIdx.x] = (i < n) ? deg[i] : 0;
  __syncthreads();
  for (int off = 128; off; off >>= 1) {
    if (threadIdx.x < off) sh[threadIdx.x] += sh[threadIdx.x + off];
    __syncthreads();
  }
  if (threadIdx.x == 0) bsum[blockIdx.x] = sh[0];
}

__global__ __launch_bounds__(256) void scan_bsums(int* __restrict__ bsum, int nb) {
  __shared__ int sh[256];
  int t = threadIdx.x;
  int v = (t < nb) ? bsum[t] : 0;
  sh[t] = v;
  __syncthreads();
  for (int off = 1; off < 256; off <<= 1) {
    int u = (t >= off) ? sh[t - off] : 0;
    __syncthreads();
    sh[t] += u;
    __syncthreads();
  }
  if (t < nb) bsum[t] = sh[t] - v;  // exclusive
}

__global__ __launch_bounds__(256) void scan_final(const int* __restrict__ deg,
                                                  const int* __restrict__ bsum,
                                                  int* __restrict__ rowptr, int n) {
  __shared__ int sh[256];
  int t = threadIdx.x;
  int i = blockIdx.x * 256 + t;
  int v = (i < n) ? deg[i] : 0;
  sh[t] = v;
  __syncthreads();
  for (int off = 1; off < 256; off <<= 1) {
    int u = (t >= off) ? sh[t - off] : 0;
    __syncthreads();
    sh[t] += u;
    __syncthreads();
  }
  if (i < n) rowptr[i + 1] = bsum[blockIdx.x] + sh[t];
  if (i == 0) rowptr[0] = 0;
}

__global__ __launch_bounds__(256) void fill_csr(const int* __restrict__ src,
                                                const int* __restrict__ dst,
                                                const int* __restrict__ rowptr,
                                                int* __restrict__ fillc,
                                                int* __restrict__ esrc, int E) {
  int e = blockIdx.x * 256 + threadIdx.x;
  if (e < E) {
    int d = dst[e];
    int pos = rowptr[d] + atomicAdd(&fillc[d], 1);
    esrc[pos] = src[e];
  }
}

// LDS-histogram batch count
__global__ __launch_bounds__(256) void bcount(const int* __restrict__ batch,
                                              float* __restrict__ bcnt, int n) {
  __shared__ int h[N_GRAPH];
  if (threadIdx.x < N_GRAPH) h[threadIdx.x] = 0;
  __syncthreads();
  int i = blockIdx.x * 256 + threadIdx.x;
  if (i < n) atomicAdd(&h[batch[i]], 1);
  __syncthreads();
  if (threadIdx.x < N_GRAPH && h[threadIdx.x])
    atomicAdd(&bcnt[threadIdx.x], (float)h[threadIdx.x]);
}

// ---------------------------------------------------------------------------
// gemm_glds v2: out[M x 512](bf16) = X[M x 512]bf16 @ W (+ bias)
// Wt = W^T bf16 [512][ldw]. 128x128 tile, BK=32, 256 thr = 4 waves (2x2).
// Fixes vs v1 (counter-driven):
//  (1) glds lane remap: source row=lane&15, seg=(lane>>4)*8 -> LDS deposit at
//      base+lane*16 == exactly the MFMA fragment address (As + chunk*512 +
//      lane*8 halfs). ds_read_b128 is linear per lane -> ZERO bank conflicts
//      (was 3.84M). Global address SET unchanged (16 rows x 64B) -> same
//      coalescing.
//  (2) epilogue bounces C through padded LDS -> uint4 row-contiguous stores
//      (WRITE_SIZE was 2.4x ideal from 2B scalar stores).
//  (3) XCD-aware swizzle: xcd = L&7, 59 strips/XCD, 4 col-blocks of a strip
//      adjacent on one XCD -> A rows fetched ~once (FETCH was 2x ideal).
// A-row OOB reads (last strip) land in the adjacent ws buffer: harmless.
// NOT in-place safe.
// ---------------------------------------------------------------------------
__global__ __launch_bounds__(256) void gemm_glds(
    const unsigned short* __restrict__ Xb, int ldx,
    const unsigned short* __restrict__ Wt, int ldw,
    const float* __restrict__ bias,
    unsigned short* __restrict__ outB, int M) {
  __shared__ __align__(16) unsigned short As[128 * 32];
  __shared__ __align__(16) unsigned short Bs[128 * 32];
  __shared__ __align__(16) unsigned short Cs[64][136];
  const int tid = threadIdx.x;
  const int L = blockIdx.x;
  const int xcd = L & 7, li = L >> 3;
  const int strip = xcd * 59 + (li >> 2);
  if (strip >= STRIPS) return;  // block-uniform early-out
  const int bm = strip * 128;
  const int bn = (li & 3) * 128;
  const int wv = tid >> 6, lane = tid & 63;
  const int wm = (wv >> 1) * 64, wn = (wv & 1) * 64;
  const int lm = lane & 15, quad = lane >> 4;
  const int grow = lane & 15, gseg = (lane >> 4) * 8;  // glds source mapping

  f32x4 zero;
  zero[0] = 0.f; zero[1] = 0.f; zero[2] = 0.f; zero[3] = 0.f;
  f32x4 acc[4][4];
#pragma unroll
  for (int i = 0; i < 4; ++i)
#pragma unroll
    for (int j = 0; j < 4; ++j) acc[i][j] = zero;

  for (int kt = 0; kt < 512; kt += 32) {
    __syncthreads();  // previous ds_reads complete before LDS overwrite
#pragma unroll
    for (int r = 0; r < 2; ++r) {
      int chunk = wv + r * 4;           // 0..7, wave-uniform
      int row = chunk * 16 + grow;      // tile row
      const unsigned short* ga = Xb + (size_t)(bm + row) * ldx + kt + gseg;
      const unsigned short* gb = Wt + (size_t)(bn + row) * ldw + kt + gseg;
      __builtin_amdgcn_global_load_lds(
          (const __attribute__((address_space(1))) unsigned int*)ga,
          (__attribute__((address_space(3))) unsigned int*)(As + chunk * 512),
          16, 0, 0);
      __builtin_amdgcn_global_load_lds(
          (const __attribute__((address_space(1))) unsigned int*)gb,
          (__attribute__((address_space(3))) unsigned int*)(Bs + chunk * 512),
          16, 0, 0);
    }
    __syncthreads();  // drains vmcnt: staged data visible
    bf16x8 af[4], bfr[4];
#pragma unroll
    for (int i = 0; i < 4; ++i)
      af[i] = *(const bf16x8*)(As + (wm / 16 + i) * 512 + lane * 8);
#pragma unroll
    for (int j = 0; j < 4; ++j)
      bfr[j] = *(const bf16x8*)(Bs + (wn / 16 + j) * 512 + lane * 8);
#pragma unroll
    for (int i = 0; i < 4; ++i)
#pragma unroll
      for (int j = 0; j < 4; ++j)
        acc[i][j] = __builtin_amdgcn_mfma_f32_16x16x32_bf16(af[i], bfr[j], acc[i][j], 0, 0, 0);
  }

  // ---- epilogue: 2 phases through Cs -> coalesced uint4 stores
  const int qr = quad * 4;
  const int rl = tid >> 4, seg = (tid & 15) * 8;
#pragma unroll
  for (int p = 0; p < 2; ++p) {
    __syncthreads();
    if ((wv >> 1) == p) {
#pragma unroll
      for (int j = 0; j < 4; ++j) {
        int col = wn + j * 16 + lm;
        float bvv = bias ? bias[bn + col] : 0.f;
#pragma unroll
        for (int i = 0; i < 4; ++i)
#pragma unroll
          for (int r = 0; r < 4; ++r)
            Cs[i * 16 + qr + r][col] = f2bf(acc[i][j][r] + bvv);
      }
    }
    __syncthreads();
#pragma unroll
    for (int pass = 0; pass < 4; ++pass) {
      int row = bm + p * 64 + pass * 16 + rl;
      if (row < M)
        *(uint4*)(outB + (size_t)row * 512 + bn + seg) =
            *(const uint4*)(&Cs[pass * 16 + rl][seg]);
    }
  }
}

// ---------------------------------------------------------------------------
// Tiled MFMA GEMM (m93 structure) — fp32-input path (embed GEMM only).
// ---------------------------------------------------------------------------
__global__ __launch_bounds__(256) void gemm_tiled(
    const float* __restrict__ Xf, int ldx, int K,
    const unsigned short* __restrict__ Wt, int ldw,
    const float* __restrict__ bias,
    unsigned short* __restrict__ outB, int M) {
  __shared__ __align__(16) unsigned short As[128][40];
  __shared__ __align__(16) unsigned short Bs[128][40];
  const int tid = threadIdx.x;
  const int bm = blockIdx.x * 128;
  const int bn = blockIdx.y * 128;
  const int wv = tid >> 6, lane = tid & 63;
  const int wm = (wv >> 1) * 64, wn = (wv & 1) * 64;
  const int lm = lane & 15, quad = lane >> 4, lk = quad * 8;
  const int srow = tid >> 2, sseg = (tid & 3) * 8;

  f32x4 zero;
  zero[0] = 0.f; zero[1] = 0.f; zero[2] = 0.f; zero[3] = 0.f;
  f32x4 acc[4][4];
#pragma unroll
  for (int i = 0; i < 4; ++i)
#pragma unroll
    for (int j = 0; j < 4; ++j) acc[i][j] = zero;

  const int r0 = bm + srow, r1 = bm + 64 + srow;
  for (int kt = 0; kt < K; kt += 32) {
    uint4 a0 = make_uint4(0, 0, 0, 0), a1 = make_uint4(0, 0, 0, 0);
    if (r0 < M) {
      const float* xp = Xf + (size_t)r0 * ldx + kt + sseg;
      float4 f0 = *(const float4*)xp, f1 = *(const float4*)(xp + 4);
      a0.x = packbf(f0.x, f0.y); a0.y = packbf(f0.z, f0.w);
      a0.z = packbf(f1.x, f1.y); a0.w = packbf(f1.z, f1.w);
    }
    if (r1 < M) {
      const float* xp = Xf + (size_t)r1 * ldx + kt + sseg;
      float4 f0 = *(const float4*)xp, f1 = *(const float4*)(xp + 4);
      a1.x = packbf(f0.x, f0.y); a1.y = packbf(f0.z, f0.w);
      a1.z = packbf(f1.x, f1.y); a1.w = packbf(f1.z, f1.w);
    }
    uint4 b0 = *(const uint4*)(Wt + (size_t)(bn + srow) * ldw + kt + sseg);
    uint4 b1 = *(const uint4*)(Wt + (size_t)(bn + 64 + srow) * ldw + kt + sseg);
    __syncthreads();
    *(uint4*)(&As[srow][sseg]) = a0;
    *(uint4*)(&As[srow + 64][sseg]) = a1;
    *(uint4*)(&Bs[srow][sseg]) = b0;
    *(uint4*)(&Bs[srow + 64][sseg]) = b1;
    __syncthreads();
    bf16x8 af[4], bfr[4];
#pragma unroll
    for (int i = 0; i < 4; ++i) af[i] = *(const bf16x8*)(&As[wm + i * 16 + lm][lk]);
#pragma unroll
    for (int j = 0; j < 4; ++j) bfr[j] = *(const bf16x8*)(&Bs[wn + j * 16 + lm][lk]);
#pragma unroll
    for (int i = 0; i < 4; ++i)
#pragma unroll
      for (int j = 0; j < 4; ++j)
        acc[i][j] = __builtin_amdgcn_mfma_f32_16x16x32_bf16(af[i], bfr[j], acc[i][j], 0, 0, 0);
  }

  const int qr = quad * 4;
#pragma unroll
  for (int j = 0; j < 4; ++j) {
    int col = bn + wn + j * 16 + lm;
    float bvv = bias ? bias[col] : 0.f;
#pragma unroll
    for (int i = 0; i < 4; ++i) {
      int rbase = bm + wm + i * 16 + qr;
#pragma unroll
      for (int r = 0; r < 4; ++r) {
        int row = rbase + r;
        if (row < M) outB[(size_t)row * 512 + col] = f2bf(acc[i][j][r] + bvv);
      }
    }
  }
}

// ---------------------------------------------------------------------------
// Row-strip MFMA GEMM — IN-PLACE SAFE fallback (used only if ws lacks B3).
// ---------------------------------------------------------------------------
__global__ __launch_bounds__(512) void gemm_strip(
    const unsigned short* __restrict__ Xb, int ldx,
    const unsigned short* __restrict__ Wt, int ldw,
    const float* __restrict__ bias,
    unsigned short* __restrict__ outB, int M) {
  __shared__ __align__(16) unsigned short As[64][40];
  const int tid = threadIdx.x;
  const int bm = blockIdx.x * 64;
  const int wv = tid >> 6, lane = tid & 63;
  const int lm = lane & 15, quad = lane >> 4, lk = quad * 8;
  const int cb = wv * 64;
  const int arow = tid >> 3, aseg = (tid & 7) * 4;

  f32x4 zero;
  zero[0] = 0.f; zero[1] = 0.f; zero[2] = 0.f; zero[3] = 0.f;
  f32x4 acc[4][4];
#pragma unroll
  for (int i = 0; i < 4; ++i)
#pragma unroll
    for (int j = 0; j < 4; ++j) acc[i][j] = zero;

  for (int kt = 0; kt < 512; kt += 32) {
    uint2 av = make_uint2(0, 0);
    int gr = bm + arow;
    if (gr < M) av = *(const uint2*)(Xb + (size_t)gr * ldx + kt + aseg);
    bf16x8 bfr[4];
#pragma unroll
    for (int j = 0; j < 4; ++j)
      bfr[j] = *(const bf16x8*)(Wt + (size_t)(cb + j * 16 + lm) * ldw + kt + lk);
    __syncthreads();
    *(uint2*)(&As[arow][aseg]) = av;
    __syncthreads();
    bf16x8 af[4];
#pragma unroll
    for (int i = 0; i < 4; ++i) af[i] = *(const bf16x8*)(&As[i * 16 + lm][lk]);
#pragma unroll
    for (int i = 0; i < 4; ++i)
#pragma unroll
      for (int j = 0; j < 4; ++j)
        acc[i][j] = __builtin_amdgcn_mfma_f32_16x16x32_bf16(af[i], bfr[j], acc[i][j], 0, 0, 0);
  }

  const int qr = quad * 4;
#pragma unroll
  for (int j = 0; j < 4; ++j) {
    int col = cb + j * 16 + lm;
    float bvv = bias ? bias[col] : 0.f;
#pragma unroll
    for (int i = 0; i < 4; ++i) {
      int rbase = bm + i * 16 + qr;
#pragma unroll
      for (int r = 0; r < 4; ++r) {
        int row = rbase + r;
        if (row < M) outB[(size_t)row * 512 + col] = f2bf(acc[i][j][r] + bvv);
      }
    }
  }
}

// ---------------------------------------------------------------------------
// Fused aggregation + L2 row-norm (one wave per dst node, CSR gather)
// ---------------------------------------------------------------------------
__global__ __launch_bounds__(256) void aggr_norm(
    unsigned short* __restrict__ Ya, const unsigned short* __restrict__ Yb,
    const int* __restrict__ rowptr, const int* __restrict__ esrc,
    const float* __restrict__ invdeg, int M) {
  int d = blockIdx.x * 4 + (threadIdx.x >> 6);
  int lane = threadIdx.x & 63;
  if (d >= M) return;
  float acc[8] = {0.f, 0.f, 0.f, 0.f, 0.f, 0.f, 0.f, 0.f};
  int beg = rowptr[d], end = rowptr[d + 1];
  for (int e = beg; e < end; ++e) {
    int s = esrc[e];
    uint4 u = *(const uint4*)(Yb + (size_t)s * 512 + lane * 8);
    acc[0] += bfLo(u.x); acc[1] += bfHi(u.x);
    acc[2] += bfLo(u.y); acc[3] += bfHi(u.y);
    acc[4] += bfLo(u.z); acc[5] += bfHi(u.z);
    acc[6] += bfLo(u.w); acc[7] += bfHi(u.w);
  }
  float iv = invdeg[d];
  uint4 a = *(const uint4*)(Ya + (size_t)d * 512 + lane * 8);
  float r0 = bfLo(a.x) + iv * acc[0], r1 = bfHi(a.x) + iv * acc[1];
  float r2 = bfLo(a.y) + iv * acc[2], r3 = bfHi(a.y) + iv * acc[3];
  float r4 = bfLo(a.z) + iv * acc[4], r5 = bfHi(a.z) + iv * acc[5];
  float r6 = bfLo(a.w) + iv * acc[6], r7 = bfHi(a.w) + iv * acc[7];
  float ss = r0 * r0 + r1 * r1 + r2 * r2 + r3 * r3
           + r4 * r4 + r5 * r5 + r6 * r6 + r7 * r7;
#pragma unroll
  for (int o = 32; o; o >>= 1) ss += __shfl_xor(ss, o, 64);
  float inv = 1.0f / fmaxf(sqrtf(ss), 1e-12f);
  uint4 o4;
  o4.x = packbf(r0 * inv, r1 * inv);
  o4.y = packbf(r2 * inv, r3 * inv);
  o4.z = packbf(r4 * inv, r5 * inv);
  o4.w = packbf(r6 * inv, r7 * inv);
  *(uint4*)(Ya + (size_t)d * 512 + lane * 8) = o4;
}

// ---------------------------------------------------------------------------
// BN stats over bf16: sums[0..511]=sum, sums[512..1023]=sumsq
// ---------------------------------------------------------------------------
__global__ __launch_bounds__(256) void bn_stats(const unsigned short* __restrict__ T,
                                                int M, float* __restrict__ sums) {
  const int t = threadIdx.x;
  int r0 = blockIdx.x * 128;
  int rend = min(r0 + 128, M);
  float s0 = 0.f, q0 = 0.f, s1 = 0.f, q1 = 0.f;
  for (int r = r0; r < rend; ++r) {
    float a = __uint_as_float((unsigned)T[(size_t)r * 512 + t] << 16);
    float b = __uint_as_float((unsigned)T[(size_t)r * 512 + t + 256] << 16);
    s0 += a; q0 += a * a; s1 += b; q1 += b * b;
  }
  atomicAdd(&sums[t], s0);
  atomicAdd(&sums[t + 256], s1);
  atomicAdd(&sums[512 + t], q0);
  atomicAdd(&sums[512 + t + 256], q1);
}

// BN apply + ReLU (+ optional residual); bf16 in/out, 2 cols per thread.
__global__ __launch_bounds__(256) void bn_apply(const unsigned short* __restrict__ U,
                                                unsigned short* __restrict__ H,
                                                const float* __restrict__ sums,
                                                const float* __restrict__ g,
                                                const float* __restrict__ be,
                                                int M, int residual) {
  size_t i2 = (size_t)blockIdx.x * 256 + threadIdx.x;
  if (i2 >= NS / 2) return;
  int c = ((int)(i2 & 255)) * 2;
  float invM = 1.0f / (float)M;
  float m0 = sums[c] * invM, m1 = sums[c + 1] * invM;
  float v0 = sums[512 + c] * invM - m0 * m0;
  float v1 = sums[512 + c + 1] * invM - m1 * m1;
  float k0 = rsqrtf(v0 + BN_EPS) * g[c], k1 = rsqrtf(v1 + BN_EPS) * g[c + 1];
  unsigned u = ((const unsigned*)U)[i2];
  float x0 = fmaxf((bfLo(u) - m0) * k0 + be[c], 0.f);
  float x1 = fmaxf((bfHi(u) - m1) * k1 + be[c + 1], 0.f);
  if (residual) {
    unsigned hv = ((const unsigned*)H)[i2];
    x0 += bfLo(hv);
    x1 += bfHi(hv);
  }
  ((unsigned*)H)[i2] = packbf(x0, x1);
}

// ---------------------------------------------------------------------------
// Attention pool, sorted-batch segmented, 64 nodes/block (938 blocks).
// ---------------------------------------------------------------------------
#define NPB 64
__global__ __launch_bounds__(256) void att_pool2(const unsigned short* __restrict__ H,
                                                 const int* __restrict__ batch,
                                                 const float* __restrict__ Watt,
                                                 float* __restrict__ hg, int M) {
  __shared__ float fsh[NPB];
  __shared__ int bsh[NPB];
  const int tid = threadIdx.x;
  const int base = blockIdx.x * NPB;
  if (tid < NPB) bsh[tid] = (base + tid < M) ? batch[base + tid] : -1;
  const int wv = tid >> 6, lane = tid & 63;
  float4 wa0 = *(const float4*)(Watt + lane * 8);
  float4 wa1 = *(const float4*)(Watt + lane * 8 + 4);
  __syncthreads();
  for (int i = wv; i < NPB; i += 4) {
    int node = base + i;
    float dot = 0.f;
    if (node < M) {
      uint4 u = *(const uint4*)(H + (size_t)node * 512 + lane * 8);
      dot = bfLo(u.x) * wa0.x + bfHi(u.x) * wa0.y
          + bfLo(u.y) * wa0.z + bfHi(u.y) * wa0.w
          + bfLo(u.z) * wa1.x + bfHi(u.z) * wa1.y
          + bfLo(u.w) * wa1.z + bfHi(u.w) * wa1.w;
    }
#pragma unroll
    for (int o = 32; o; o >>= 1) dot += __shfl_xor(dot, o, 64);
    if (lane == 0) fsh[i] = 0.5f * (1.0f + 1.0f / (1.0f + expf(-dot)));
  }
  __syncthreads();
  float a0 = 0.f, a1 = 0.f;
  int cur = bsh[0];
  for (int i = 0; i < NPB; ++i) {
    int node = base + i;
    if (node >= M) break;
    int b = bsh[i];
    if (b != cur) {
      atomicAdd(&hg[(size_t)cur * 512 + tid * 2], a0);
      atomicAdd(&hg[(size_t)cur * 512 + tid * 2 + 1], a1);
      a0 = a1 = 0.f;
      cur = b;
    }
    unsigned u = *(const unsigned*)(H + (size_t)node * 512 + tid * 2);
    float f = fsh[i];
    a0 += bfLo(u) * f;
    a1 += bfHi(u) * f;
  }
  if (cur >= 0) {
    atomicAdd(&hg[(size_t)cur * 512 + tid * 2], a0);
    atomicAdd(&hg[(size_t)cur * 512 + tid * 2 + 1], a1);
  }
}

// ---------------------------------------------------------------------------
// Readout: out[g, n] = (hg[g]/bcnt[g]) . Wread[:, n]
// ---------------------------------------------------------------------------
__global__ __launch_bounds__(256) void readout(const float* __restrict__ hg,
                                               const float* __restrict__ bcnt,
                                               const float* __restrict__ Wr,
                                               float* __restrict__ out) {
  __shared__ float sh[HID];
  int g = blockIdx.x;
  int n = blockIdx.y * 256 + threadIdx.x;
  float inv = 1.0f / fmaxf(bcnt[g], 1.0f);
  for (int k = threadIdx.x; k < HID; k += 256) sh[k] = hg[(size_t)g * HID + k] * inv;
  __syncthreads();
  if (n < NCLS) {
    float acc = 0.f;
    for (int k = 0; k < HID; ++k) acc += sh[k] * Wr[(size_t)k * NCLS + n];
    out[(size_t)g * NCLS + n] = acc;
  }
}

// ---------------------------------------------------------------------------
extern "C" void kernel_launch(void* const* d_in, const int* in_sizes, int n_in,
                              void* d_out, int out_size, void* d_ws, size_t ws_size,
                              hipStream_t stream) {
  const float* x       = (const float*)d_in[0];
  const int*   ei      = (const int*)d_in[1];
  const int*   batch   = (const int*)d_in[2];
  const float* W_embed = (const float*)d_in[3];
  const float* W1      = (const float*)d_in[4];
  const float* b1      = (const float*)d_in[5];
  const float* g1      = (const float*)d_in[6];
  const float* be1     = (const float*)d_in[7];
  const float* W2      = (const float*)d_in[8];
  const float* b2      = (const float*)d_in[9];
  const float* g2      = (const float*)d_in[10];
  const float* be2     = (const float*)d_in[11];
  const float* Watt    = (const float*)d_in[12];
  const float* Wread   = (const float*)d_in[13];
  float* out = (float*)d_out;

  const int* srcIdx = ei;
  const int* dstIdx = ei + N_EDGES;

  char* p = (char*)d_ws;
  unsigned short* B0 = (unsigned short*)p; p += NS * 2;   // h (residual)
  unsigned short* B1 = (unsigned short*)p; p += NS * 2;   // Ya / T
  unsigned short* B2 = (unsigned short*)p; p += NS * 2;   // Yb
  unsigned short* WtE = (unsigned short*)p; p += (size_t)512 * 256 * 2;
  unsigned short* Wt1 = (unsigned short*)p; p += (size_t)3 * 512 * 1024 * 2;
  unsigned short* Wt2 = (unsigned short*)p; p += (size_t)3 * 512 * 1024 * 2;
  float* hg     = (float*)p; p += (size_t)N_GRAPH * HID * 4;
  float* sums   = (float*)p; p += 1024 * 4;
  float* invdeg = (float*)p; p += (size_t)N_NODES * 4;
  float* bcnt   = (float*)p; p += 256;
  int* deg      = (int*)p;   p += (size_t)N_NODES * 4;
  int* fillc    = (int*)p;   p += (size_t)N_NODES * 4;
  int* esrc     = (int*)p;   p += (size_t)N_EDGES * 4;
  int* rowptr   = (int*)p;   p += (size_t)(N_NODES + 1) * 4;
  int* bsum     = (int*)p;   p += (size_t)NB * 4;
  size_t need3 = (size_t)(p - (char*)d_ws);
  if (ws_size < need3) {
    write_sentinel<<<1, 1, 0, stream>>>(out, (float)need3);
    return;
  }
  // optional 4th activation buffer -> no in-place GEMM at all
  unsigned short* B3 = nullptr;
  if (ws_size >= need3 + NS * 2 + 65536) B3 = (unsigned short*)((char*)d_ws + need3);

  // ---- weight prep (fp32 -> bf16, transposed [N][K])
  wtrans<<<dim3(8, 16), 256, 0, stream>>>(W_embed, WtE, 256, 512);
  for (int l = 0; l < 3; ++l) {
    wtrans<<<dim3(32, 16), 256, 0, stream>>>(W1 + (size_t)l * 1024 * 512,
                                             Wt1 + (size_t)l * 512 * 1024, 1024, 512);
    wtrans<<<dim3(32, 16), 256, 0, stream>>>(W2 + (size_t)l * 1024 * 512,
                                             Wt2 + (size_t)l * 512 * 1024, 1024, 512);
  }

  // ---- CSR build (parallel scan)
  hipMemsetAsync(deg, 0, N_NODES * sizeof(int), stream);
  hipMemsetAsync(fillc, 0, N_NODES * sizeof(int), stream);
  count_deg<<<(N_EDGES + 255) / 256, 256, 0, stream>>>(dstIdx, deg, N_EDGES);
  make_invdeg<<<(N_NODES + 255) / 256, 256, 0, stream>>>(deg, invdeg, N_NODES);
  scan_part<<<NB, 256, 0, stream>>>(deg, bsum, N_NODES);
  scan_bsums<<<1, 256, 0, stream>>>(bsum, NB);
  scan_final<<<NB, 256, 0, stream>>>(deg, bsum, rowptr, N_NODES);
  fill_csr<<<(N_EDGES + 255) / 256, 256, 0, stream>>>(srcIdx, dstIdx, rowptr, fillc,
                                                      esrc, N_EDGES);

  const int ggrid = 8 * 59 * 4;  // XCD-swizzled 1-D grid (1888 blocks)
  const dim3 tgrid((N_NODES + 127) / 128, 4);
  const int sgrid = (N_NODES + 63) / 64;
  const int ngrid = (N_NODES + 3) / 4;
  const int egrid = (int)((NS / 2 + 255) / 256);

  // h = x @ W_embed (fp32 input -> staging-convert path)
  gemm_tiled<<<tgrid, 256, 0, stream>>>(x, 256, 256, WtE, 256, nullptr, B0, N_NODES);

  for (int l = 0; l < 3; ++l) {
    const unsigned short* Wt1l = Wt1 + (size_t)l * 512 * 1024;
    const unsigned short* Wt2l = Wt2 + (size_t)l * 512 * 1024;
    // ---- SAGE 1: B1 = bn(norm(B0@Wa1 + gather(B0@Wb1)))
    gemm_glds<<<ggrid, 256, 0, stream>>>(B0, 512, Wt1l + 512, 1024,
                                         nullptr, B2, N_NODES);        // Yb
    gemm_glds<<<ggrid, 256, 0, stream>>>(B0, 512, Wt1l, 1024,
                                         b1 + l * 512, B1, N_NODES);   // Ya
    aggr_norm<<<ngrid, 256, 0, stream>>>(B1, B2, rowptr, esrc, invdeg, N_NODES);
    hipMemsetAsync(sums, 0, 1024 * sizeof(float), stream);
    bn_stats<<<(N_NODES + 127) / 128, 256, 0, stream>>>(B1, N_NODES, sums);
    bn_apply<<<egrid, 256, 0, stream>>>(B1, B1, sums, g1 + l * 512,
                                        be1 + l * 512, N_NODES, 0);
    // ---- SAGE 2 + residual: B0 += relu(bn(norm(B1@Wa2 + gather(B1@Wb2))))
    gemm_glds<<<ggrid, 256, 0, stream>>>(B1, 512, Wt2l + 512, 1024,
                                         nullptr, B2, N_NODES);        // Yb
    unsigned short* Ya2 = B3 ? B3 : B1;
    if (B3) {
      gemm_glds<<<ggrid, 256, 0, stream>>>(B1, 512, Wt2l, 1024,
                                           b2 + l * 512, B3, N_NODES);
    } else {
      gemm_strip<<<sgrid, 512, 0, stream>>>(B1, 512, Wt2l, 1024,
                                            b2 + l * 512, B1, N_NODES);  // in-place safe
    }
    aggr_norm<<<ngrid, 256, 0, stream>>>(Ya2, B2, rowptr, esrc, invdeg, N_NODES);
    hipMemsetAsync(sums, 0, 1024 * sizeof(float), stream);
    bn_stats<<<(N_NODES + 127) / 128, 256, 0, stream>>>(Ya2, N_NODES, sums);
    bn_apply<<<egrid, 256, 0, stream>>>(Ya2, B0, sums, g2 + l * 512,
                                        be2 + l * 512, N_NODES, 1);
  }

  // ---- pooling + readout
  hipMemsetAsync(hg, 0, (size_t)N_GRAPH * HID * sizeof(float), stream);
  hipMemsetAsync(bcnt, 0, N_GRAPH * sizeof(float), stream);
  bcount<<<NB, 256, 0, stream>>>(batch, bcnt, N_NODES);
  att_pool2<<<(N_NODES + NPB - 1) / NPB, 256, 0, stream>>>(B0, batch, Watt, hg, N_NODES);
  readout<<<dim3(N_GRAPH, 4), 256, 0, stream>>>(hg, bcnt, Wread, out);
}